// Round 10
// baseline (955.878 us; speedup 1.0000x reference)
//
#include <hip/hip_runtime.h>
#include <hip/hip_bf16.h>
#include <math.h>

#define NNODES 65536
#define NEDGES 1048576
#define NGRAPHS 64

typedef __attribute__((ext_vector_type(8))) short short8;
typedef __attribute__((ext_vector_type(4))) float f32x4;

// ---- order-preserving float<->uint encoding for atomicMax-based max ----
__device__ __forceinline__ unsigned encf(float f) {
    unsigned u = __float_as_uint(f);
    return (u & 0x80000000u) ? ~u : (u | 0x80000000u);
}
__device__ __forceinline__ float decf(unsigned u) {
    unsigned v = (u & 0x80000000u) ? (u & 0x7FFFFFFFu) : ~u;
    return __uint_as_float(v);
}
#define ENC_NEG_INF 0x007FFFFFu   // encf(-inf)

// RNE float -> bf16 bits (finite values only) — cold paths only
__device__ __forceinline__ unsigned bfbits(float f) {
    unsigned u = __float_as_uint(f);
    return (u + 0x7FFFu + ((u >> 16) & 1u)) >> 16;
}
// HOT path: HW packed RNE convert (1 VALU op / 2 elems), T12 recipe.
__device__ __forceinline__ unsigned pk2(float a, float b) {
    unsigned r;
    asm("v_cvt_pk_bf16_f32 %0, %1, %2" : "=v"(r) : "v"(a), "v"(b));
    return r;   // a -> low 16, b -> high 16 (S0 packs low)
}
__device__ __forceinline__ float bflo(unsigned p) { return __uint_as_float(p << 16); }
__device__ __forceinline__ float bfhi(unsigned p) { return __uint_as_float(p & 0xFFFF0000u); }

// ============================ CSR build ============================
__global__ void k_init(int* deg, int* cursor, unsigned* poolEnc) {
    int i = blockIdx.x * 256 + threadIdx.x;
    if (i < NNODES) { deg[i] = 0; cursor[i] = 0; }
    if (i < NGRAPHS * 256) poolEnc[i] = ENC_NEG_INF;
}

__global__ void k_count(const int* __restrict__ ei, int* deg) {
    int e = blockIdx.x * 256 + threadIdx.x;
    atomicAdd(&deg[ei[NEDGES + e]], 1);
}

__global__ void k_scan1(const int* __restrict__ deg, int* rowptr, int* bsum) {
    __shared__ int s[256];
    int t = threadIdx.x, b = blockIdx.x;
    int v = deg[b * 256 + t];
    s[t] = v;
    __syncthreads();
    for (int off = 1; off < 256; off <<= 1) {
        int x = (t >= off) ? s[t - off] : 0;
        __syncthreads();
        if (t >= off) s[t] += x;
        __syncthreads();
    }
    rowptr[b * 256 + t] = s[t] - v;       // local exclusive
    if (t == 255) bsum[b] = s[255];
}

__global__ void k_scan2(const int* __restrict__ bsum, int* boff) {
    __shared__ int s[256];
    int t = threadIdx.x;
    int v = bsum[t];
    s[t] = v;
    __syncthreads();
    for (int off = 1; off < 256; off <<= 1) {
        int x = (t >= off) ? s[t - off] : 0;
        __syncthreads();
        if (t >= off) s[t] += x;
        __syncthreads();
    }
    boff[t] = s[t] - v;                   // exclusive block offsets
}

__global__ void k_scan3(int* rowptr, const int* __restrict__ boff) {
    int i = blockIdx.x * 256 + threadIdx.x;
    rowptr[i] += boff[blockIdx.x];
    if (i == 0) rowptr[NNODES] = NEDGES;
}

__global__ void k_scatter(const int* __restrict__ ei, const int* __restrict__ rowptr,
                          int* cursor, int* csr_src, int* csr_dst) {
    int e = blockIdx.x * 256 + threadIdx.x;
    int s = ei[e], d = ei[NEDGES + e];
    int pos = rowptr[d] + atomicAdd(&cursor[d], 1);
    csr_src[pos] = s;
    csr_dst[pos] = d;
}

// ============================ U/V precompute ============================
// U[i] = X[i] @ (W1_top - W1_bot) + b1  (fp32, dst-local, L1-cached in k_agg)
// V[i] = X[i] @ W1_bot                  (bf16: the random-gathered operand)
template <int FIN, int H>
__global__ __launch_bounds__(256) void k_uv(const float* __restrict__ X,
                                            const float* __restrict__ W1,
                                            const float* __restrict__ B1,
                                            float* __restrict__ U,
                                            unsigned short* __restrict__ Vb) {
    constexpr int NPT = (16 * H) / 256;   // nodes per thread
    __shared__ float xs[16][FIN];
    int tid = threadIdx.x;
    int n0 = blockIdx.x * 16;
    for (int idx = tid; idx < 16 * FIN; idx += 256)
        xs[idx / FIN][idx % FIN] = X[(size_t)(n0 + idx / FIN) * FIN + (idx % FIN)];
    __syncthreads();
    int h = tid & (H - 1);
    int nb = (tid / H) * NPT;
    float u[NPT], v[NPT];
    float bb = B1[h];
#pragma unroll
    for (int n = 0; n < NPT; n++) { u[n] = bb; v[n] = 0.f; }
    for (int f = 0; f < FIN; f++) {
        float wt = W1[f * H + h];
        float wb = W1[(FIN + f) * H + h];
        float wd = wt - wb;
#pragma unroll
        for (int n = 0; n < NPT; n++) {
            float xv = xs[nb + n][f];
            u[n] += xv * wd;
            v[n] += xv * wb;
        }
    }
#pragma unroll
    for (int n = 0; n < NPT; n++) {
        U[(size_t)(n0 + nb + n) * H + h] = u[n];
        Vb[(size_t)(n0 + nb + n) * H + h] = (unsigned short)bfbits(v[n]);
    }
}

// ================= fused edge-GEMM (MFMA bf16) + segment-max =================
// Block owns 16 dst nodes + all their in-edges (CSR) -> no global atomics.
// Round-5 base + (a) pk2 via v_cvt_pk_bf16_f32, (b) all-rows-same-slot atomic
// fold. ROUNDS 8/9 BUG (identical absmax both rounds -> fold, not pk2):
// `quadUni && (x == __shfl_xor(x,16)) && ...` short-circuits; quadUni is
// per-quad DIVERGENT, so shuffles ran under a divergent exec mask and read
// undefined lanes -> spurious allUni -> cross-slot max merge. FIX: issue the
// shuffles UNCONDITIONALLY (wave fully active here) and reduce via __all()
// so the branch is wave-uniform before any further cross-lane op.
template <int H, int F, int RWAVES, int CWAVES>
__global__ __launch_bounds__(RWAVES * CWAVES * 64)
void k_agg(const float* __restrict__ U,
           const unsigned short* __restrict__ Vb,
           const float* __restrict__ W2,
           const float* __restrict__ B2,
           const int* __restrict__ rowptr,
           const int* __restrict__ csr_src,
           const int* __restrict__ csr_dst,
           float* __restrict__ Y) {
    constexpr int BLOCK = RWAVES * CWAVES * 64;
    constexpr int TR = 32 * RWAVES;         // edge rows per tile
    constexpr int HP = H + 8;               // padded row (bf16 units), 16B-aligned frags
    constexpr int CPW = F / CWAVES;         // cols per wave
    constexpr int NT = CPW / 16;            // n-tiles per wave
    constexpr int KS = H / 32;              // k-steps
    constexpr int ACCSTR = F + 16;          // slot stride: 16-bank offset per slot
    constexpr int LPR = H / 8;              // threads per hidden row (8 elems each)
    constexpr int RPP = BLOCK / LPR;        // rows per construction pass
    constexpr int NPASS = TR / RPP;         // construction passes per tile
    static_assert(H % 32 == 0 && NT >= 1 && RPP >= 1 && TR % RPP == 0, "shape");

    __shared__ unsigned short hs[2][TR * HP];   // double-buffered hidden tile
    __shared__ unsigned accs[16 * ACCSTR];      // per-slot running max (encoded)
    __shared__ int srcA[2][TR];
    __shared__ __align__(4) signed char slotB[2][TR];

    int tid = threadIdx.x;
    int n0 = blockIdx.x * 16;

    int ln = tid & 15;              // MFMA n/m lane index
    int qd = (tid >> 4) & 3;        // MFMA quad
    int wv = tid >> 6;
    int rw = wv / CWAVES;           // row group
    int cw = wv % CWAVES;           // col wave

    // ---- load W2 fragments into registers (bf16), once ----
    short8 Bf[NT][KS];
#pragma unroll
    for (int nt = 0; nt < NT; nt++) {
        int col = cw * CPW + nt * 16 + ln;
#pragma unroll
        for (int ks = 0; ks < KS; ks++) {
            int kb = ks * 32 + qd * 8;
            short8 b;
#pragma unroll
            for (int j = 0; j < 8; j++)
                b[j] = (short)bfbits(W2[(size_t)(kb + j) * F + col]);
            Bf[nt][ks] = b;
        }
    }

    for (int idx = tid; idx < 16 * ACCSTR; idx += BLOCK) accs[idx] = ENC_NEG_INF;

    int e0 = rowptr[n0], e1 = rowptr[n0 + 16];
    int ntile = (e1 - e0 + TR - 1) / TR;

    int rid = tid / LPR;            // construction: my row within a pass
    int kk = (tid % LPR) * 8;       // construction: my 8-elem chunk

    // stage CSR metadata for tile 0
    if (tid < TR) {
        int p = e0 + tid;
        int s = 0; signed char sl = -1;
        if (p < e1) { s = csr_src[p]; sl = (signed char)(csr_dst[p] - n0); }
        srcA[0][tid] = s; slotB[0][tid] = sl;
    }
    __syncthreads();

    // MFMA + segmented-max for one completed tile (reads hs[buf])
    auto mfma_tile = [&](int buf, char4 s0, char4 s1) {
        f32x4 acc[2][NT];
#pragma unroll
        for (int mt = 0; mt < 2; mt++)
#pragma unroll
            for (int nt = 0; nt < NT; nt++)
                acc[mt][nt] = (f32x4){0.f, 0.f, 0.f, 0.f};

        __builtin_amdgcn_s_setprio(1);
#pragma unroll
        for (int ks = 0; ks < KS; ks++) {
            int ko = ks * 32 + qd * 8;
            short8 a0 = *(const short8*)&hs[buf][(rw * 32 + ln) * HP + ko];
            short8 a1 = *(const short8*)&hs[buf][(rw * 32 + 16 + ln) * HP + ko];
#pragma unroll
            for (int nt = 0; nt < NT; nt++) {
                acc[0][nt] = __builtin_amdgcn_mfma_f32_16x16x32_bf16(a0, Bf[nt][ks], acc[0][nt], 0, 0, 0);
                acc[1][nt] = __builtin_amdgcn_mfma_f32_16x16x32_bf16(a1, Bf[nt][ks], acc[1][nt], 0, 0, 0);
            }
        }
        __builtin_amdgcn_s_setprio(0);

#pragma unroll
        for (int mt = 0; mt < 2; mt++) {
            char4 ss = mt ? s1 : s0;
            int sInt = *(const int*)&ss;
            // Exec-mask-safe uniformity check: shuffles issued by the WHOLE
            // wave (no divergence yet), then __all() makes the flag uniform.
            int s16 = __shfl_xor(sInt, 16);
            int s32 = __shfl_xor(sInt, 32);
            bool quadUni = (ss.x == ss.y) && (ss.y == ss.z) && (ss.z == ss.w);
            bool allUni = __all(quadUni && (sInt == s16) && (sInt == s32)) != 0;
#pragma unroll
            for (int nt = 0; nt < NT; nt++) {
                int colw = cw * CPW + nt * 16 + ln;
                float c0 = acc[mt][nt][0], c1 = acc[mt][nt][1];
                float c2 = acc[mt][nt][2], c3 = acc[mt][nt][3];
                float m3 = c3;
                float m2 = (ss.z == ss.w) ? fmaxf(c2, m3) : c2;
                float m1 = (ss.y == ss.z) ? fmaxf(c1, m2) : c1;
                float m0 = (ss.x == ss.y) ? fmaxf(c0, m1) : c0;
                if (allUni) {
                    // wave-uniform branch; all 64 lanes active for the fold
                    float v = m0;                       // max of my quad's 4 rows
                    v = fmaxf(v, __shfl_xor(v, 16));
                    v = fmaxf(v, __shfl_xor(v, 32));    // now max of all 16 rows
                    if (qd == 0 && ss.x >= 0)
                        atomicMax(&accs[(int)ss.x * ACCSTR + colw], encf(v));
                } else {
                    if (ss.x >= 0)                 atomicMax(&accs[(int)ss.x * ACCSTR + colw], encf(m0));
                    if (ss.y >= 0 && ss.y != ss.x) atomicMax(&accs[(int)ss.y * ACCSTR + colw], encf(m1));
                    if (ss.z >= 0 && ss.z != ss.y) atomicMax(&accs[(int)ss.z * ACCSTR + colw], encf(m2));
                    if (ss.w >= 0 && ss.w != ss.z) atomicMax(&accs[(int)ss.w * ACCSTR + colw], encf(m3));
                }
            }
        }
    };

    char4 ssp0 = make_char4(-1, -1, -1, -1), ssp1 = make_char4(-1, -1, -1, -1);
    int prevbuf = 0;

    for (int t = 0; t < ntile; t++) {
        int cur = t & 1;

        // (1) capture tile-t metadata; issue gathered-V loads EARLY
        int msrc[NPASS]; int msl[NPASS];
#pragma unroll
        for (int ps = 0; ps < NPASS; ps++) {
            int r = ps * RPP + rid;
            msrc[ps] = srcA[cur][r];
            msl[ps] = slotB[cur][r];
        }
        uint4 vreg[NPASS];
#pragma unroll
        for (int ps = 0; ps < NPASS; ps++)
            vreg[ps] = *(const uint4*)&Vb[(size_t)msrc[ps] * H + kk];   // src=0 for pad rows: safe
        char4 ssc0 = *(const char4*)&slotB[cur][rw * 32 + qd * 4];
        char4 ssc1 = *(const char4*)&slotB[cur][rw * 32 + 16 + qd * 4];

        // (2) prefetch CSR metadata for tile t+1 into registers
        int nsrc = 0; signed char nsl = -1;
        bool hn = (t + 1 < ntile);
        if (hn && tid < TR) {
            int p = e0 + (t + 1) * TR + tid;
            if (p < e1) { nsrc = csr_src[p]; nsl = (signed char)(csr_dst[p] - n0); }
        }

        // (3) MFMA + seg-max for tile t-1 — hides the V-gather latency
        if (t > 0) mfma_tile(prevbuf, ssp0, ssp1);

        // (4) build hidden tile t: hs = bf16(relu(U[dst] + V[src]))
#pragma unroll
        for (int ps = 0; ps < NPASS; ps++) {
            int r = ps * RPP + rid;
            uint4 w;
            if (msl[ps] >= 0) {
                const float4 ua = *(const float4*)&U[(size_t)(n0 + msl[ps]) * H + kk];
                const float4 ub = *(const float4*)&U[(size_t)(n0 + msl[ps]) * H + kk + 4];
                const uint4 vv = vreg[ps];
                w.x = pk2(fmaxf(ua.x + bflo(vv.x), 0.f), fmaxf(ua.y + bfhi(vv.x), 0.f));
                w.y = pk2(fmaxf(ua.z + bflo(vv.y), 0.f), fmaxf(ua.w + bfhi(vv.y), 0.f));
                w.z = pk2(fmaxf(ub.x + bflo(vv.z), 0.f), fmaxf(ub.y + bfhi(vv.z), 0.f));
                w.w = pk2(fmaxf(ub.z + bflo(vv.w), 0.f), fmaxf(ub.w + bfhi(vv.w), 0.f));
            } else {
                w = (uint4){0u, 0u, 0u, 0u};
            }
            *(uint4*)&hs[cur][r * HP + kk] = w;
        }

        // (5) stage next tile's CSR metadata into the other buffer
        if (hn && tid < TR) { srcA[cur ^ 1][tid] = nsrc; slotB[cur ^ 1][tid] = nsl; }

        // (6) single barrier per tile
        __syncthreads();
        ssp0 = ssc0; ssp1 = ssc1; prevbuf = cur;
    }
    if (ntile > 0) mfma_tile(prevbuf, ssp0, ssp1);
    __syncthreads();

    for (int idx = tid; idx < 16 * F; idx += BLOCK) {
        int sl = idx / F, cc = idx % F;
        float m = decf(accs[sl * ACCSTR + cc]);
        float o = isfinite(m) ? (m + B2[cc]) : 0.f;   // empty segment -> 0
        Y[(size_t)(n0 + sl) * F + cc] = o;
    }
}

// ============================ global max-pool + FC ============================
__global__ void k_pool(const float* __restrict__ X3, const int* __restrict__ batch,
                       unsigned* poolEnc) {
    int gph = blockIdx.x;
    int seg = blockIdx.y;
    int c = threadIdx.x;
    int lo = 0, hi = NNODES;
    while (lo < hi) { int mid = (lo + hi) >> 1; if (batch[mid] < gph) lo = mid + 1; else hi = mid; }
    int start = lo;
    hi = NNODES;
    while (lo < hi) { int mid = (lo + hi) >> 1; if (batch[mid] < gph + 1) lo = mid + 1; else hi = mid; }
    int end = lo;
    int chunk = (end - start + 7) >> 3;
    int s = start + seg * chunk;
    int e = min(end, s + chunk);
    float m = -INFINITY;
    for (int n = s; n < e; n++) m = fmaxf(m, X3[(size_t)n * 256 + c]);
    atomicMax(&poolEnc[gph * 256 + c], encf(m));
}

__global__ __launch_bounds__(128) void k_fc(const unsigned* __restrict__ poolEnc,
                                            const float* __restrict__ Wfc,
                                            const float* __restrict__ Bfc,
                                            float* __restrict__ out) {
    __shared__ float p[256];
    int gph = blockIdx.x, c = threadIdx.x;
    for (int k = c; k < 256; k += 128) {
        float m = decf(poolEnc[gph * 256 + k]);
        p[k] = isfinite(m) ? m : 0.f;
    }
    __syncthreads();
    float s = Bfc[c];
    for (int k = 0; k < 256; k++) s += p[k] * Wfc[k * 128 + c];
    out[gph * 128 + c] = s;
}

// ============================ launch ============================
extern "C" void kernel_launch(void* const* d_in, const int* in_sizes, int n_in,
                              void* d_out, int out_size, void* d_ws, size_t ws_size,
                              hipStream_t stream) {
    const float* x     = (const float*)d_in[0];
    const int*   ei    = (const int*)d_in[1];
    const int*   batch = (const int*)d_in[2];
    const float* w1_1 = (const float*)d_in[3];
    const float* b1_1 = (const float*)d_in[4];
    const float* w2_1 = (const float*)d_in[5];
    const float* b2_1 = (const float*)d_in[6];
    const float* w1_2 = (const float*)d_in[7];
    const float* b1_2 = (const float*)d_in[8];
    const float* w2_2 = (const float*)d_in[9];
    const float* b2_2 = (const float*)d_in[10];
    const float* w1_3 = (const float*)d_in[11];
    const float* b1_3 = (const float*)d_in[12];
    const float* w2_3 = (const float*)d_in[13];
    const float* b2_3 = (const float*)d_in[14];
    const float* wfc  = (const float*)d_in[15];
    const float* bfc  = (const float*)d_in[16];
    float* out = (float*)d_out;

    char* ws = (char*)d_ws;
    size_t off = 0;
    auto alloc = [&](size_t bytes) {
        void* p = ws + off;
        off = (off + bytes + 255) & ~(size_t)255;
        return p;
    };
    int* deg      = (int*)alloc((size_t)NNODES * 4);
    int* cursor   = (int*)alloc((size_t)NNODES * 4);
    int* rowptr   = (int*)alloc((size_t)(NNODES + 1) * 4);
    int* bsum     = (int*)alloc(256 * 4);
    int* boff     = (int*)alloc(256 * 4);
    int* csr_src  = (int*)alloc((size_t)NEDGES * 4);
    int* csr_dst  = (int*)alloc((size_t)NEDGES * 4);
    float* U      = (float*)alloc((size_t)NNODES * 256 * 4);
    unsigned short* V = (unsigned short*)alloc((size_t)NNODES * 256 * 2);
    float* x1     = (float*)alloc((size_t)NNODES * 64 * 4);
    float* x2     = (float*)alloc((size_t)NNODES * 128 * 4);
    float* x3     = (float*)alloc((size_t)NNODES * 256 * 4);
    unsigned* poolEnc = (unsigned*)alloc((size_t)NGRAPHS * 256 * 4);
    (void)ws_size; (void)in_sizes; (void)n_in; (void)out_size;

    // CSR by dst (shared across the 3 layers)
    k_init<<<256, 256, 0, stream>>>(deg, cursor, poolEnc);
    k_count<<<NEDGES / 256, 256, 0, stream>>>(ei, deg);
    k_scan1<<<256, 256, 0, stream>>>(deg, rowptr, bsum);
    k_scan2<<<1, 256, 0, stream>>>(bsum, boff);
    k_scan3<<<256, 256, 0, stream>>>(rowptr, boff);
    k_scatter<<<NEDGES / 256, 256, 0, stream>>>(ei, rowptr, cursor, csr_src, csr_dst);

    // layer 1: F_in=3, H=64, F=64   (2x2 waves, TR=64, NPASS=2)
    k_uv<3, 64><<<NNODES / 16, 256, 0, stream>>>(x, w1_1, b1_1, U, V);
    k_agg<64, 64, 2, 2><<<NNODES / 16, 256, 0, stream>>>(U, V, w2_1, b2_1, rowptr, csr_src, csr_dst, x1);
    // layer 2: F_in=64, H=128, F=128  (1x8 waves, 512 thr, CPW=16)
    k_uv<64, 128><<<NNODES / 16, 256, 0, stream>>>(x1, w1_2, b1_2, U, V);
    k_agg<128, 128, 1, 8><<<NNODES / 16, 512, 0, stream>>>(U, V, w2_2, b2_2, rowptr, csr_src, csr_dst, x2);
    // layer 3: F_in=128, H=256, F=256  (1x16 waves, 1024 thr, CPW=16)
    k_uv<128, 256><<<NNODES / 16, 256, 0, stream>>>(x2, w1_3, b1_3, U, V);
    k_agg<256, 256, 1, 16><<<NNODES / 16, 1024, 0, stream>>>(U, V, w2_3, b2_3, rowptr, csr_src, csr_dst, x3);

    // global max pool + FC
    k_pool<<<dim3(NGRAPHS, 8), 256, 0, stream>>>(x3, batch, poolEnc);
    k_fc<<<NGRAPHS, 128, 0, stream>>>(poolEnc, wfc, bfc, out);
}

// Round 11
// 891.328 us; speedup vs baseline: 1.0724x; 1.0724x over previous
//
#include <hip/hip_runtime.h>
#include <hip/hip_bf16.h>
#include <math.h>

#define NNODES 65536
#define NEDGES 1048576
#define NGRAPHS 64

typedef __attribute__((ext_vector_type(8))) short short8;
typedef __attribute__((ext_vector_type(4))) float f32x4;

// ---- order-preserving float<->uint encoding for atomicMax-based max ----
__device__ __forceinline__ unsigned encf(float f) {
    unsigned u = __float_as_uint(f);
    return (u & 0x80000000u) ? ~u : (u | 0x80000000u);
}
__device__ __forceinline__ float decf(unsigned u) {
    unsigned v = (u & 0x80000000u) ? (u & 0x7FFFFFFFu) : ~u;
    return __uint_as_float(v);
}
#define ENC_NEG_INF 0x007FFFFFu   // encf(-inf)

// RNE float -> bf16 bits (finite values only) — cold paths only
__device__ __forceinline__ unsigned bfbits(float f) {
    unsigned u = __float_as_uint(f);
    return (u + 0x7FFFu + ((u >> 16) & 1u)) >> 16;
}
// HOT path: HW packed RNE convert (1 VALU op / 2 elems). Round-8 lesson:
// __float2bfloat16 is NOT RNE on this toolchain; v_cvt_pk_bf16_f32 is RNE
// in HW and matches bfbits (verified passing in round 10).
__device__ __forceinline__ unsigned pk2(float a, float b) {
    unsigned r;
    asm("v_cvt_pk_bf16_f32 %0, %1, %2" : "=v"(r) : "v"(a), "v"(b));
    return r;   // a -> low 16, b -> high 16
}
__device__ __forceinline__ float bflo(unsigned p) { return __uint_as_float(p << 16); }
__device__ __forceinline__ float bfhi(unsigned p) { return __uint_as_float(p & 0xFFFF0000u); }

// ============================ CSR build ============================
__global__ void k_init(int* deg, int* cursor, unsigned* poolEnc) {
    int i = blockIdx.x * 256 + threadIdx.x;
    if (i < NNODES) { deg[i] = 0; cursor[i] = 0; }
    if (i < NGRAPHS * 256) poolEnc[i] = ENC_NEG_INF;
}

__global__ void k_count(const int* __restrict__ ei, int* deg) {
    int e = blockIdx.x * 256 + threadIdx.x;
    atomicAdd(&deg[ei[NEDGES + e]], 1);
}

__global__ void k_scan1(const int* __restrict__ deg, int* rowptr, int* bsum) {
    __shared__ int s[256];
    int t = threadIdx.x, b = blockIdx.x;
    int v = deg[b * 256 + t];
    s[t] = v;
    __syncthreads();
    for (int off = 1; off < 256; off <<= 1) {
        int x = (t >= off) ? s[t - off] : 0;
        __syncthreads();
        if (t >= off) s[t] += x;
        __syncthreads();
    }
    rowptr[b * 256 + t] = s[t] - v;       // local exclusive
    if (t == 255) bsum[b] = s[255];
}

__global__ void k_scan2(const int* __restrict__ bsum, int* boff) {
    __shared__ int s[256];
    int t = threadIdx.x;
    int v = bsum[t];
    s[t] = v;
    __syncthreads();
    for (int off = 1; off < 256; off <<= 1) {
        int x = (t >= off) ? s[t - off] : 0;
        __syncthreads();
        if (t >= off) s[t] += x;
        __syncthreads();
    }
    boff[t] = s[t] - v;                   // exclusive block offsets
}

__global__ void k_scan3(int* rowptr, const int* __restrict__ boff) {
    int i = blockIdx.x * 256 + threadIdx.x;
    rowptr[i] += boff[blockIdx.x];
    if (i == 0) rowptr[NNODES] = NEDGES;
}

__global__ void k_scatter(const int* __restrict__ ei, const int* __restrict__ rowptr,
                          int* cursor, int* csr_src, int* csr_dst) {
    int e = blockIdx.x * 256 + threadIdx.x;
    int s = ei[e], d = ei[NEDGES + e];
    int pos = rowptr[d] + atomicAdd(&cursor[d], 1);
    csr_src[pos] = s;
    csr_dst[pos] = d;
}

// ============================ U/V precompute ============================
// U[i] = X[i] @ (W1_top - W1_bot) + b1  (fp32, dst-local, L1-cached in k_agg)
// V[i] = X[i] @ W1_bot                  (bf16: the random-gathered operand)
template <int FIN, int H>
__global__ __launch_bounds__(256) void k_uv(const float* __restrict__ X,
                                            const float* __restrict__ W1,
                                            const float* __restrict__ B1,
                                            float* __restrict__ U,
                                            unsigned short* __restrict__ Vb) {
    constexpr int NPT = (16 * H) / 256;   // nodes per thread
    __shared__ float xs[16][FIN];
    int tid = threadIdx.x;
    int n0 = blockIdx.x * 16;
    for (int idx = tid; idx < 16 * FIN; idx += 256)
        xs[idx / FIN][idx % FIN] = X[(size_t)(n0 + idx / FIN) * FIN + (idx % FIN)];
    __syncthreads();
    int h = tid & (H - 1);
    int nb = (tid / H) * NPT;
    float u[NPT], v[NPT];
    float bb = B1[h];
#pragma unroll
    for (int n = 0; n < NPT; n++) { u[n] = bb; v[n] = 0.f; }
    for (int f = 0; f < FIN; f++) {
        float wt = W1[f * H + h];
        float wb = W1[(FIN + f) * H + h];
        float wd = wt - wb;
#pragma unroll
        for (int n = 0; n < NPT; n++) {
            float xv = xs[nb + n][f];
            u[n] += xv * wd;
            v[n] += xv * wb;
        }
    }
#pragma unroll
    for (int n = 0; n < NPT; n++) {
        U[(size_t)(n0 + nb + n) * H + h] = u[n];
        Vb[(size_t)(n0 + nb + n) * H + h] = (unsigned short)bfbits(v[n]);
    }
}

// ================= fused edge-GEMM (MFMA bf16) + segment-max =================
// Block owns 16 dst nodes + all their in-edges (CSR) -> no global atomics.
// Round-5 structure (best verified, 931 us): register-lean CPW=16 shapes,
// double-buffered hidden tile, ONE barrier per tile, V-gathers + next-tile
// CSR issued before the previous tile's MFMA. Only addition: pk2 via
// v_cvt_pk_bf16_f32 (RNE; cuts construction VALU ~2.5x).
// Round-10 lesson (reverted): shfl-based atomic folding ADDS DS-pipe ops
// (ds_swizzle shares the LDS pipe, the kernel's bottleneck) -> +24 us.
template <int H, int F, int RWAVES, int CWAVES>
__global__ __launch_bounds__(RWAVES * CWAVES * 64)
void k_agg(const float* __restrict__ U,
           const unsigned short* __restrict__ Vb,
           const float* __restrict__ W2,
           const float* __restrict__ B2,
           const int* __restrict__ rowptr,
           const int* __restrict__ csr_src,
           const int* __restrict__ csr_dst,
           float* __restrict__ Y) {
    constexpr int BLOCK = RWAVES * CWAVES * 64;
    constexpr int TR = 32 * RWAVES;         // edge rows per tile
    constexpr int HP = H + 8;               // padded row (bf16 units), 16B-aligned frags
    constexpr int CPW = F / CWAVES;         // cols per wave
    constexpr int NT = CPW / 16;            // n-tiles per wave
    constexpr int KS = H / 32;              // k-steps
    constexpr int ACCSTR = F + 1;           // bank-spread accumulator stride
    constexpr int LPR = H / 8;              // threads per hidden row (8 elems each)
    constexpr int RPP = BLOCK / LPR;        // rows per construction pass
    constexpr int NPASS = TR / RPP;         // construction passes per tile
    static_assert(H % 32 == 0 && NT >= 1 && RPP >= 1 && TR % RPP == 0, "shape");

    __shared__ unsigned short hs[2][TR * HP];   // double-buffered hidden tile
    __shared__ unsigned accs[16 * ACCSTR];      // per-slot running max (encoded)
    __shared__ int srcA[2][TR];
    __shared__ __align__(4) signed char slotB[2][TR];

    int tid = threadIdx.x;
    int n0 = blockIdx.x * 16;

    int ln = tid & 15;              // MFMA n/m lane index
    int qd = (tid >> 4) & 3;        // MFMA quad
    int wv = tid >> 6;
    int rw = wv / CWAVES;           // row group
    int cw = wv % CWAVES;           // col wave

    // ---- load W2 fragments into registers (bf16), once ----
    short8 Bf[NT][KS];
#pragma unroll
    for (int nt = 0; nt < NT; nt++) {
        int col = cw * CPW + nt * 16 + ln;
#pragma unroll
        for (int ks = 0; ks < KS; ks++) {
            int kb = ks * 32 + qd * 8;
            short8 b;
#pragma unroll
            for (int j = 0; j < 8; j++)
                b[j] = (short)bfbits(W2[(size_t)(kb + j) * F + col]);
            Bf[nt][ks] = b;
        }
    }

    for (int idx = tid; idx < 16 * ACCSTR; idx += BLOCK) accs[idx] = ENC_NEG_INF;

    int e0 = rowptr[n0], e1 = rowptr[n0 + 16];
    int ntile = (e1 - e0 + TR - 1) / TR;

    int rid = tid / LPR;            // construction: my row within a pass
    int kk = (tid % LPR) * 8;       // construction: my 8-elem chunk

    // stage CSR metadata for tile 0
    if (tid < TR) {
        int p = e0 + tid;
        int s = 0; signed char sl = -1;
        if (p < e1) { s = csr_src[p]; sl = (signed char)(csr_dst[p] - n0); }
        srcA[0][tid] = s; slotB[0][tid] = sl;
    }
    __syncthreads();

    // MFMA + segmented-max for one completed tile (reads hs[buf])
    auto mfma_tile = [&](int buf, char4 s0, char4 s1) {
        f32x4 acc[2][NT];
#pragma unroll
        for (int mt = 0; mt < 2; mt++)
#pragma unroll
            for (int nt = 0; nt < NT; nt++)
                acc[mt][nt] = (f32x4){0.f, 0.f, 0.f, 0.f};

#pragma unroll
        for (int ks = 0; ks < KS; ks++) {
            int ko = ks * 32 + qd * 8;
            short8 a0 = *(const short8*)&hs[buf][(rw * 32 + ln) * HP + ko];
            short8 a1 = *(const short8*)&hs[buf][(rw * 32 + 16 + ln) * HP + ko];
#pragma unroll
            for (int nt = 0; nt < NT; nt++) {
                acc[0][nt] = __builtin_amdgcn_mfma_f32_16x16x32_bf16(a0, Bf[nt][ks], acc[0][nt], 0, 0, 0);
                acc[1][nt] = __builtin_amdgcn_mfma_f32_16x16x32_bf16(a1, Bf[nt][ks], acc[1][nt], 0, 0, 0);
            }
        }

#pragma unroll
        for (int mt = 0; mt < 2; mt++) {
            char4 ss = mt ? s1 : s0;
#pragma unroll
            for (int nt = 0; nt < NT; nt++) {
                int colw = cw * CPW + nt * 16 + ln;
                float c0 = acc[mt][nt][0], c1 = acc[mt][nt][1];
                float c2 = acc[mt][nt][2], c3 = acc[mt][nt][3];
                float m3 = c3;
                float m2 = (ss.z == ss.w) ? fmaxf(c2, m3) : c2;
                float m1 = (ss.y == ss.z) ? fmaxf(c1, m2) : c1;
                float m0 = (ss.x == ss.y) ? fmaxf(c0, m1) : c0;
                if (ss.x >= 0)                 atomicMax(&accs[(int)ss.x * ACCSTR + colw], encf(m0));
                if (ss.y >= 0 && ss.y != ss.x) atomicMax(&accs[(int)ss.y * ACCSTR + colw], encf(m1));
                if (ss.z >= 0 && ss.z != ss.y) atomicMax(&accs[(int)ss.z * ACCSTR + colw], encf(m2));
                if (ss.w >= 0 && ss.w != ss.z) atomicMax(&accs[(int)ss.w * ACCSTR + colw], encf(m3));
            }
        }
    };

    char4 ssp0 = make_char4(-1, -1, -1, -1), ssp1 = make_char4(-1, -1, -1, -1);
    int prevbuf = 0;

    for (int t = 0; t < ntile; t++) {
        int cur = t & 1;

        // (1) capture tile-t metadata; issue gathered-V loads EARLY
        int msrc[NPASS]; int msl[NPASS];
#pragma unroll
        for (int ps = 0; ps < NPASS; ps++) {
            int r = ps * RPP + rid;
            msrc[ps] = srcA[cur][r];
            msl[ps] = slotB[cur][r];
        }
        uint4 vreg[NPASS];
#pragma unroll
        for (int ps = 0; ps < NPASS; ps++)
            vreg[ps] = *(const uint4*)&Vb[(size_t)msrc[ps] * H + kk];   // src=0 for pad rows: safe
        char4 ssc0 = *(const char4*)&slotB[cur][rw * 32 + qd * 4];
        char4 ssc1 = *(const char4*)&slotB[cur][rw * 32 + 16 + qd * 4];

        // (2) prefetch CSR metadata for tile t+1 into registers
        int nsrc = 0; signed char nsl = -1;
        bool hn = (t + 1 < ntile);
        if (hn && tid < TR) {
            int p = e0 + (t + 1) * TR + tid;
            if (p < e1) { nsrc = csr_src[p]; nsl = (signed char)(csr_dst[p] - n0); }
        }

        // (3) MFMA + seg-max for tile t-1 — hides the V-gather latency
        if (t > 0) mfma_tile(prevbuf, ssp0, ssp1);

        // (4) build hidden tile t: hs = bf16(relu(U[dst] + V[src]))
#pragma unroll
        for (int ps = 0; ps < NPASS; ps++) {
            int r = ps * RPP + rid;
            uint4 w;
            if (msl[ps] >= 0) {
                const float4 ua = *(const float4*)&U[(size_t)(n0 + msl[ps]) * H + kk];
                const float4 ub = *(const float4*)&U[(size_t)(n0 + msl[ps]) * H + kk + 4];
                const uint4 vv = vreg[ps];
                w.x = pk2(fmaxf(ua.x + bflo(vv.x), 0.f), fmaxf(ua.y + bfhi(vv.x), 0.f));
                w.y = pk2(fmaxf(ua.z + bflo(vv.y), 0.f), fmaxf(ua.w + bfhi(vv.y), 0.f));
                w.z = pk2(fmaxf(ub.x + bflo(vv.z), 0.f), fmaxf(ub.y + bfhi(vv.z), 0.f));
                w.w = pk2(fmaxf(ub.z + bflo(vv.w), 0.f), fmaxf(ub.w + bfhi(vv.w), 0.f));
            } else {
                w = (uint4){0u, 0u, 0u, 0u};
            }
            *(uint4*)&hs[cur][r * HP + kk] = w;
        }

        // (5) stage next tile's CSR metadata into the other buffer
        if (hn && tid < TR) { srcA[cur ^ 1][tid] = nsrc; slotB[cur ^ 1][tid] = nsl; }

        // (6) single barrier per tile
        __syncthreads();
        ssp0 = ssc0; ssp1 = ssc1; prevbuf = cur;
    }
    if (ntile > 0) mfma_tile(prevbuf, ssp0, ssp1);
    __syncthreads();

    for (int idx = tid; idx < 16 * F; idx += BLOCK) {
        int sl = idx / F, cc = idx % F;
        float m = decf(accs[sl * ACCSTR + cc]);
        float o = isfinite(m) ? (m + B2[cc]) : 0.f;   // empty segment -> 0
        Y[(size_t)(n0 + sl) * F + cc] = o;
    }
}

// ============================ global max-pool + FC ============================
__global__ void k_pool(const float* __restrict__ X3, const int* __restrict__ batch,
                       unsigned* poolEnc) {
    int gph = blockIdx.x;
    int seg = blockIdx.y;
    int c = threadIdx.x;
    int lo = 0, hi = NNODES;
    while (lo < hi) { int mid = (lo + hi) >> 1; if (batch[mid] < gph) lo = mid + 1; else hi = mid; }
    int start = lo;
    hi = NNODES;
    while (lo < hi) { int mid = (lo + hi) >> 1; if (batch[mid] < gph + 1) lo = mid + 1; else hi = mid; }
    int end = lo;
    int chunk = (end - start + 7) >> 3;
    int s = start + seg * chunk;
    int e = min(end, s + chunk);
    float m = -INFINITY;
    for (int n = s; n < e; n++) m = fmaxf(m, X3[(size_t)n * 256 + c]);
    atomicMax(&poolEnc[gph * 256 + c], encf(m));
}

__global__ __launch_bounds__(128) void k_fc(const unsigned* __restrict__ poolEnc,
                                            const float* __restrict__ Wfc,
                                            const float* __restrict__ Bfc,
                                            float* __restrict__ out) {
    __shared__ float p[256];
    int gph = blockIdx.x, c = threadIdx.x;
    for (int k = c; k < 256; k += 128) {
        float m = decf(poolEnc[gph * 256 + k]);
        p[k] = isfinite(m) ? m : 0.f;
    }
    __syncthreads();
    float s = Bfc[c];
    for (int k = 0; k < 256; k++) s += p[k] * Wfc[k * 128 + c];
    out[gph * 128 + c] = s;
}

// ============================ launch ============================
extern "C" void kernel_launch(void* const* d_in, const int* in_sizes, int n_in,
                              void* d_out, int out_size, void* d_ws, size_t ws_size,
                              hipStream_t stream) {
    const float* x     = (const float*)d_in[0];
    const int*   ei    = (const int*)d_in[1];
    const int*   batch = (const int*)d_in[2];
    const float* w1_1 = (const float*)d_in[3];
    const float* b1_1 = (const float*)d_in[4];
    const float* w2_1 = (const float*)d_in[5];
    const float* b2_1 = (const float*)d_in[6];
    const float* w1_2 = (const float*)d_in[7];
    const float* b1_2 = (const float*)d_in[8];
    const float* w2_2 = (const float*)d_in[9];
    const float* b2_2 = (const float*)d_in[10];
    const float* w1_3 = (const float*)d_in[11];
    const float* b1_3 = (const float*)d_in[12];
    const float* w2_3 = (const float*)d_in[13];
    const float* b2_3 = (const float*)d_in[14];
    const float* wfc  = (const float*)d_in[15];
    const float* bfc  = (const float*)d_in[16];
    float* out = (float*)d_out;

    char* ws = (char*)d_ws;
    size_t off = 0;
    auto alloc = [&](size_t bytes) {
        void* p = ws + off;
        off = (off + bytes + 255) & ~(size_t)255;
        return p;
    };
    int* deg      = (int*)alloc((size_t)NNODES * 4);
    int* cursor   = (int*)alloc((size_t)NNODES * 4);
    int* rowptr   = (int*)alloc((size_t)(NNODES + 1) * 4);
    int* bsum     = (int*)alloc(256 * 4);
    int* boff     = (int*)alloc(256 * 4);
    int* csr_src  = (int*)alloc((size_t)NEDGES * 4);
    int* csr_dst  = (int*)alloc((size_t)NEDGES * 4);
    float* U      = (float*)alloc((size_t)NNODES * 256 * 4);
    unsigned short* V = (unsigned short*)alloc((size_t)NNODES * 256 * 2);
    float* x1     = (float*)alloc((size_t)NNODES * 64 * 4);
    float* x2     = (float*)alloc((size_t)NNODES * 128 * 4);
    float* x3     = (float*)alloc((size_t)NNODES * 256 * 4);
    unsigned* poolEnc = (unsigned*)alloc((size_t)NGRAPHS * 256 * 4);
    (void)ws_size; (void)in_sizes; (void)n_in; (void)out_size;

    // CSR by dst (shared across the 3 layers)
    k_init<<<256, 256, 0, stream>>>(deg, cursor, poolEnc);
    k_count<<<NEDGES / 256, 256, 0, stream>>>(ei, deg);
    k_scan1<<<256, 256, 0, stream>>>(deg, rowptr, bsum);
    k_scan2<<<1, 256, 0, stream>>>(bsum, boff);
    k_scan3<<<256, 256, 0, stream>>>(rowptr, boff);
    k_scatter<<<NEDGES / 256, 256, 0, stream>>>(ei, rowptr, cursor, csr_src, csr_dst);

    // layer 1: F_in=3, H=64, F=64   (2x2 waves, TR=64, NPASS=2)
    k_uv<3, 64><<<NNODES / 16, 256, 0, stream>>>(x, w1_1, b1_1, U, V);
    k_agg<64, 64, 2, 2><<<NNODES / 16, 256, 0, stream>>>(U, V, w2_1, b2_1, rowptr, csr_src, csr_dst, x1);
    // layer 2: F_in=64, H=128, F=128  (1x8 waves, 512 thr, CPW=16)
    k_uv<64, 128><<<NNODES / 16, 256, 0, stream>>>(x1, w1_2, b1_2, U, V);
    k_agg<128, 128, 1, 8><<<NNODES / 16, 512, 0, stream>>>(U, V, w2_2, b2_2, rowptr, csr_src, csr_dst, x2);
    // layer 3: F_in=128, H=256, F=256  (1x16 waves, 1024 thr, CPW=16)
    k_uv<128, 256><<<NNODES / 16, 256, 0, stream>>>(x2, w1_3, b1_3, U, V);
    k_agg<256, 256, 1, 16><<<NNODES / 16, 1024, 0, stream>>>(U, V, w2_3, b2_3, rowptr, csr_src, csr_dst, x3);

    // global max pool + FC
    k_pool<<<dim3(NGRAPHS, 8), 256, 0, stream>>>(x3, batch, poolEnc);
    k_fc<<<NGRAPHS, 128, 0, stream>>>(poolEnc, wfc, bfc, out);
}

// Round 12
// 784.969 us; speedup vs baseline: 1.2177x; 1.1355x over previous
//
#include <hip/hip_runtime.h>
#include <hip/hip_bf16.h>
#include <math.h>

#define NNODES 65536
#define NEDGES 1048576
#define NGRAPHS 64

typedef __attribute__((ext_vector_type(8))) short short8;
typedef __attribute__((ext_vector_type(4))) float f32x4;

// ---- order-preserving float<->uint encoding for atomicMax-based max ----
__device__ __forceinline__ unsigned encf(float f) {
    unsigned u = __float_as_uint(f);
    return (u & 0x80000000u) ? ~u : (u | 0x80000000u);
}
__device__ __forceinline__ float decf(unsigned u) {
    unsigned v = (u & 0x80000000u) ? (u & 0x7FFFFFFFu) : ~u;
    return __uint_as_float(v);
}
#define ENC_NEG_INF 0x007FFFFFu   // encf(-inf)

// RNE float -> bf16 bits (finite values only)
__device__ __forceinline__ unsigned bfbits(float f) {
    unsigned u = __float_as_uint(f);
    return (u + 0x7FFFu + ((u >> 16) & 1u)) >> 16;
}
__device__ __forceinline__ float bfval(unsigned bits) { return __uint_as_float(bits << 16); }
// HOT path: HW packed RNE convert (1 VALU op / 2 elems). Round-8 lesson:
// __float2bfloat16 is NOT RNE on this toolchain; v_cvt_pk_bf16_f32 is RNE
// in HW and matches bfbits (verified passing rounds 10-11).
__device__ __forceinline__ unsigned pk2(float a, float b) {
    unsigned r;
    asm("v_cvt_pk_bf16_f32 %0, %1, %2" : "=v"(r) : "v"(a), "v"(b));
    return r;   // a -> low 16, b -> high 16
}
__device__ __forceinline__ float bflo(unsigned p) { return __uint_as_float(p << 16); }
__device__ __forceinline__ float bfhi(unsigned p) { return __uint_as_float(p & 0xFFFF0000u); }

// ============================ CSR build ============================
__global__ void k_init(int* deg, int* cursor, unsigned* poolEnc) {
    int i = blockIdx.x * 256 + threadIdx.x;
    if (i < NNODES) { deg[i] = 0; cursor[i] = 0; }
    if (i < NGRAPHS * 256) poolEnc[i] = ENC_NEG_INF;
}

__global__ void k_count(const int* __restrict__ ei, int* deg) {
    int e = blockIdx.x * 256 + threadIdx.x;
    atomicAdd(&deg[ei[NEDGES + e]], 1);
}

__global__ void k_scan1(const int* __restrict__ deg, int* rowptr, int* bsum) {
    __shared__ int s[256];
    int t = threadIdx.x, b = blockIdx.x;
    int v = deg[b * 256 + t];
    s[t] = v;
    __syncthreads();
    for (int off = 1; off < 256; off <<= 1) {
        int x = (t >= off) ? s[t - off] : 0;
        __syncthreads();
        if (t >= off) s[t] += x;
        __syncthreads();
    }
    rowptr[b * 256 + t] = s[t] - v;       // local exclusive
    if (t == 255) bsum[b] = s[255];
}

__global__ void k_scan2(const int* __restrict__ bsum, int* boff) {
    __shared__ int s[256];
    int t = threadIdx.x;
    int v = bsum[t];
    s[t] = v;
    __syncthreads();
    for (int off = 1; off < 256; off <<= 1) {
        int x = (t >= off) ? s[t - off] : 0;
        __syncthreads();
        if (t >= off) s[t] += x;
        __syncthreads();
    }
    boff[t] = s[t] - v;                   // exclusive block offsets
}

__global__ void k_scan3(int* rowptr, const int* __restrict__ boff) {
    int i = blockIdx.x * 256 + threadIdx.x;
    rowptr[i] += boff[blockIdx.x];
    if (i == 0) rowptr[NNODES] = NEDGES;
}

__global__ void k_scatter(const int* __restrict__ ei, const int* __restrict__ rowptr,
                          int* cursor, int* csr_src, int* csr_dst) {
    int e = blockIdx.x * 256 + threadIdx.x;
    int s = ei[e], d = ei[NEDGES + e];
    int pos = rowptr[d] + atomicAdd(&cursor[d], 1);
    csr_src[pos] = s;
    csr_dst[pos] = d;
}

// ============================ U/V precompute ============================
// U[i] = X[i] @ (W1_top - W1_bot) + b1  (fp32, dst-local, L1-cached in k_agg)
// V[i] = X[i] @ W1_bot                  (bf16: the random-gathered operand)
// Scalar VALU version — kept for layer 1 only (FIN=3: no MFMA fit).
template <int FIN, int H>
__global__ __launch_bounds__(256) void k_uv(const float* __restrict__ X,
                                            const float* __restrict__ W1,
                                            const float* __restrict__ B1,
                                            float* __restrict__ U,
                                            unsigned short* __restrict__ Vb) {
    constexpr int NPT = (16 * H) / 256;   // nodes per thread
    __shared__ float xs[16][FIN];
    int tid = threadIdx.x;
    int n0 = blockIdx.x * 16;
    for (int idx = tid; idx < 16 * FIN; idx += 256)
        xs[idx / FIN][idx % FIN] = X[(size_t)(n0 + idx / FIN) * FIN + (idx % FIN)];
    __syncthreads();
    int h = tid & (H - 1);
    int nb = (tid / H) * NPT;
    float u[NPT], v[NPT];
    float bb = B1[h];
#pragma unroll
    for (int n = 0; n < NPT; n++) { u[n] = bb; v[n] = 0.f; }
    for (int f = 0; f < FIN; f++) {
        float wt = W1[f * H + h];
        float wb = W1[(FIN + f) * H + h];
        float wd = wt - wb;
#pragma unroll
        for (int n = 0; n < NPT; n++) {
            float xv = xs[nb + n][f];
            u[n] += xv * wd;
            v[n] += xv * wb;
        }
    }
#pragma unroll
    for (int n = 0; n < NPT; n++) {
        U[(size_t)(n0 + nb + n) * H + h] = u[n];
        Vb[(size_t)(n0 + nb + n) * H + h] = (unsigned short)bfbits(v[n]);
    }
}

// ==================== U/V precompute via MFMA (layers 2,3) ====================
// The old k_uv is a VALU-fp32 GEMM (~90-120us layer 3: 2048 scalar ds_reads +
// 4096 v_fma per thread). MFMA-ize with SPLIT PRECISION: X and W each split
// into bf16 hi+lo; S = Xhi@Whi + Xhi@Wlo + Xlo@Whi (fp32 accum) -> error
// ~2^-18 relative == fp32-path accuracy. Neglected term Xlo@Wlo ~2^-18.
// Fragment layouts mirror the VERIFIED k_agg: A row=ln, k=qd*8+j;
// B col=ln, k=qd*8+j; C/D row=qd*4+j, col=ln  [m89].
// Per wave: 16 cols of H; W planes in regs (KS*4 short8); X tiles through LDS.
template <int FIN, int H>
__global__ __launch_bounds__((H / 16) * 64)
void k_uv_mfma(const float* __restrict__ X,
               const float* __restrict__ W1,
               const float* __restrict__ B1,
               float* __restrict__ U,
               unsigned short* __restrict__ Vb) {
    constexpr int WAVES = H / 16;
    constexpr int BLOCK = WAVES * 64;
    constexpr int KS = FIN / 32;          // k-steps
    constexpr int NPB = 16;               // node-tiles (of 16) per block
    constexpr int FP = FIN + 8;           // padded LDS row (bf16 units)
    static_assert(FIN % 32 == 0 && (16 * FIN) % (2 * BLOCK) == 0, "shape");

    __shared__ unsigned short xhi[16 * FP];
    __shared__ unsigned short xlo[16 * FP];

    int tid = threadIdx.x;
    int ln = tid & 15;
    int qd = (tid >> 4) & 3;
    int wv = tid >> 6;
    int col = wv * 16 + ln;

    // ---- W fragment planes (bf16 hi/lo, top & bottom halves), once ----
    short8 bth[KS], btl[KS], bbh[KS], bbl[KS];
#pragma unroll
    for (int ks = 0; ks < KS; ks++) {
        int kb = ks * 32 + qd * 8;
        short8 th, tl, bh, bl;
#pragma unroll
        for (int j = 0; j < 8; j++) {
            float wt = W1[(size_t)(kb + j) * H + col];
            float wb = W1[(size_t)(FIN + kb + j) * H + col];
            unsigned thb = bfbits(wt), bhb = bfbits(wb);
            th[j] = (short)thb;
            bh[j] = (short)bhb;
            tl[j] = (short)bfbits(wt - bfval(thb));
            bl[j] = (short)bfbits(wb - bfval(bhb));
        }
        bth[ks] = th; btl[ks] = tl; bbh[ks] = bh; bbl[ks] = bl;
    }

    float bias = B1[col];
    int nbase0 = blockIdx.x * (NPB * 16);

    // staging assignment: 2 consecutive floats per thread
    int sidx = tid * 2;
    int snode = sidx / FIN;               // 0..15
    int sf = sidx % FIN;

    float2 xr = *(const float2*)&X[(size_t)(nbase0 + snode) * FIN + sf];

    for (int t = 0; t < NPB; t++) {
        // write tile t into LDS as hi/lo bf16 planes
        unsigned h0 = bfbits(xr.x), h1 = bfbits(xr.y);
        unsigned l0 = bfbits(xr.x - bfval(h0));
        unsigned l1 = bfbits(xr.y - bfval(h1));
        *(unsigned*)&xhi[snode * FP + sf] = h0 | (h1 << 16);
        *(unsigned*)&xlo[snode * FP + sf] = l0 | (l1 << 16);
        // prefetch tile t+1 (latency hides under MFMA phase)
        if (t + 1 < NPB)
            xr = *(const float2*)&X[(size_t)(nbase0 + (t + 1) * 16 + snode) * FIN + sf];
        __syncthreads();

        f32x4 at = (f32x4){0.f, 0.f, 0.f, 0.f};
        f32x4 ab = (f32x4){0.f, 0.f, 0.f, 0.f};
#pragma unroll
        for (int ks = 0; ks < KS; ks++) {
            int ko = ks * 32 + qd * 8;
            short8 ah = *(const short8*)&xhi[ln * FP + ko];
            short8 al = *(const short8*)&xlo[ln * FP + ko];
            at = __builtin_amdgcn_mfma_f32_16x16x32_bf16(ah, bth[ks], at, 0, 0, 0);
            at = __builtin_amdgcn_mfma_f32_16x16x32_bf16(ah, btl[ks], at, 0, 0, 0);
            at = __builtin_amdgcn_mfma_f32_16x16x32_bf16(al, bth[ks], at, 0, 0, 0);
            ab = __builtin_amdgcn_mfma_f32_16x16x32_bf16(ah, bbh[ks], ab, 0, 0, 0);
            ab = __builtin_amdgcn_mfma_f32_16x16x32_bf16(ah, bbl[ks], ab, 0, 0, 0);
            ab = __builtin_amdgcn_mfma_f32_16x16x32_bf16(al, bbh[ks], ab, 0, 0, 0);
        }

        int nb = nbase0 + t * 16 + qd * 4;
#pragma unroll
        for (int j = 0; j < 4; j++) {
            U[(size_t)(nb + j) * H + col] = at[j] - ab[j] + bias;   // X@(Wt-Wb)+b
            Vb[(size_t)(nb + j) * H + col] = (unsigned short)bfbits(ab[j]); // X@Wb
        }
        __syncthreads();   // tile consumed before next overwrite
    }
}

// ================= fused edge-GEMM (MFMA bf16) + segment-max =================
// Block owns 16 dst nodes + all their in-edges (CSR) -> no global atomics.
// Round-5 structure (verified best): register-lean CPW=16 shapes,
// double-buffered hidden tile, ONE barrier per tile, V-gathers + next-tile
// CSR issued before the previous tile's MFMA; pk2 via v_cvt_pk_bf16_f32.
template <int H, int F, int RWAVES, int CWAVES>
__global__ __launch_bounds__(RWAVES * CWAVES * 64)
void k_agg(const float* __restrict__ U,
           const unsigned short* __restrict__ Vb,
           const float* __restrict__ W2,
           const float* __restrict__ B2,
           const int* __restrict__ rowptr,
           const int* __restrict__ csr_src,
           const int* __restrict__ csr_dst,
           float* __restrict__ Y) {
    constexpr int BLOCK = RWAVES * CWAVES * 64;
    constexpr int TR = 32 * RWAVES;         // edge rows per tile
    constexpr int HP = H + 8;               // padded row (bf16 units), 16B-aligned frags
    constexpr int CPW = F / CWAVES;         // cols per wave
    constexpr int NT = CPW / 16;            // n-tiles per wave
    constexpr int KS = H / 32;              // k-steps
    constexpr int ACCSTR = F + 1;           // bank-spread accumulator stride
    constexpr int LPR = H / 8;              // threads per hidden row (8 elems each)
    constexpr int RPP = BLOCK / LPR;        // rows per construction pass
    constexpr int NPASS = TR / RPP;         // construction passes per tile
    static_assert(H % 32 == 0 && NT >= 1 && RPP >= 1 && TR % RPP == 0, "shape");

    __shared__ unsigned short hs[2][TR * HP];   // double-buffered hidden tile
    __shared__ unsigned accs[16 * ACCSTR];      // per-slot running max (encoded)
    __shared__ int srcA[2][TR];
    __shared__ __align__(4) signed char slotB[2][TR];

    int tid = threadIdx.x;
    int n0 = blockIdx.x * 16;

    int ln = tid & 15;              // MFMA n/m lane index
    int qd = (tid >> 4) & 3;        // MFMA quad
    int wv = tid >> 6;
    int rw = wv / CWAVES;           // row group
    int cw = wv % CWAVES;           // col wave

    // ---- load W2 fragments into registers (bf16), once ----
    short8 Bf[NT][KS];
#pragma unroll
    for (int nt = 0; nt < NT; nt++) {
        int col = cw * CPW + nt * 16 + ln;
#pragma unroll
        for (int ks = 0; ks < KS; ks++) {
            int kb = ks * 32 + qd * 8;
            short8 b;
#pragma unroll
            for (int j = 0; j < 8; j++)
                b[j] = (short)bfbits(W2[(size_t)(kb + j) * F + col]);
            Bf[nt][ks] = b;
        }
    }

    for (int idx = tid; idx < 16 * ACCSTR; idx += BLOCK) accs[idx] = ENC_NEG_INF;

    int e0 = rowptr[n0], e1 = rowptr[n0 + 16];
    int ntile = (e1 - e0 + TR - 1) / TR;

    int rid = tid / LPR;            // construction: my row within a pass
    int kk = (tid % LPR) * 8;       // construction: my 8-elem chunk

    // stage CSR metadata for tile 0
    if (tid < TR) {
        int p = e0 + tid;
        int s = 0; signed char sl = -1;
        if (p < e1) { s = csr_src[p]; sl = (signed char)(csr_dst[p] - n0); }
        srcA[0][tid] = s; slotB[0][tid] = sl;
    }
    __syncthreads();

    // MFMA + segmented-max for one completed tile (reads hs[buf])
    auto mfma_tile = [&](int buf, char4 s0, char4 s1) {
        f32x4 acc[2][NT];
#pragma unroll
        for (int mt = 0; mt < 2; mt++)
#pragma unroll
            for (int nt = 0; nt < NT; nt++)
                acc[mt][nt] = (f32x4){0.f, 0.f, 0.f, 0.f};

#pragma unroll
        for (int ks = 0; ks < KS; ks++) {
            int ko = ks * 32 + qd * 8;
            short8 a0 = *(const short8*)&hs[buf][(rw * 32 + ln) * HP + ko];
            short8 a1 = *(const short8*)&hs[buf][(rw * 32 + 16 + ln) * HP + ko];
#pragma unroll
            for (int nt = 0; nt < NT; nt++) {
                acc[0][nt] = __builtin_amdgcn_mfma_f32_16x16x32_bf16(a0, Bf[nt][ks], acc[0][nt], 0, 0, 0);
                acc[1][nt] = __builtin_amdgcn_mfma_f32_16x16x32_bf16(a1, Bf[nt][ks], acc[1][nt], 0, 0, 0);
            }
        }

#pragma unroll
        for (int mt = 0; mt < 2; mt++) {
            char4 ss = mt ? s1 : s0;
#pragma unroll
            for (int nt = 0; nt < NT; nt++) {
                int colw = cw * CPW + nt * 16 + ln;
                float c0 = acc[mt][nt][0], c1 = acc[mt][nt][1];
                float c2 = acc[mt][nt][2], c3 = acc[mt][nt][3];
                float m3 = c3;
                float m2 = (ss.z == ss.w) ? fmaxf(c2, m3) : c2;
                float m1 = (ss.y == ss.z) ? fmaxf(c1, m2) : c1;
                float m0 = (ss.x == ss.y) ? fmaxf(c0, m1) : c0;
                if (ss.x >= 0)                 atomicMax(&accs[(int)ss.x * ACCSTR + colw], encf(m0));
                if (ss.y >= 0 && ss.y != ss.x) atomicMax(&accs[(int)ss.y * ACCSTR + colw], encf(m1));
                if (ss.z >= 0 && ss.z != ss.y) atomicMax(&accs[(int)ss.z * ACCSTR + colw], encf(m2));
                if (ss.w >= 0 && ss.w != ss.z) atomicMax(&accs[(int)ss.w * ACCSTR + colw], encf(m3));
            }
        }
    };

    char4 ssp0 = make_char4(-1, -1, -1, -1), ssp1 = make_char4(-1, -1, -1, -1);
    int prevbuf = 0;

    for (int t = 0; t < ntile; t++) {
        int cur = t & 1;

        // (1) capture tile-t metadata; issue gathered-V loads EARLY
        int msrc[NPASS]; int msl[NPASS];
#pragma unroll
        for (int ps = 0; ps < NPASS; ps++) {
            int r = ps * RPP + rid;
            msrc[ps] = srcA[cur][r];
            msl[ps] = slotB[cur][r];
        }
        uint4 vreg[NPASS];
#pragma unroll
        for (int ps = 0; ps < NPASS; ps++)
            vreg[ps] = *(const uint4*)&Vb[(size_t)msrc[ps] * H + kk];   // src=0 for pad rows: safe
        char4 ssc0 = *(const char4*)&slotB[cur][rw * 32 + qd * 4];
        char4 ssc1 = *(const char4*)&slotB[cur][rw * 32 + 16 + qd * 4];

        // (2) prefetch CSR metadata for tile t+1 into registers
        int nsrc = 0; signed char nsl = -1;
        bool hn = (t + 1 < ntile);
        if (hn && tid < TR) {
            int p = e0 + (t + 1) * TR + tid;
            if (p < e1) { nsrc = csr_src[p]; nsl = (signed char)(csr_dst[p] - n0); }
        }

        // (3) MFMA + seg-max for tile t-1 — hides the V-gather latency
        if (t > 0) mfma_tile(prevbuf, ssp0, ssp1);

        // (4) build hidden tile t: hs = bf16(relu(U[dst] + V[src]))
#pragma unroll
        for (int ps = 0; ps < NPASS; ps++) {
            int r = ps * RPP + rid;
            uint4 w;
            if (msl[ps] >= 0) {
                const float4 ua = *(const float4*)&U[(size_t)(n0 + msl[ps]) * H + kk];
                const float4 ub = *(const float4*)&U[(size_t)(n0 + msl[ps]) * H + kk + 4];
                const uint4 vv = vreg[ps];
                w.x = pk2(fmaxf(ua.x + bflo(vv.x), 0.f), fmaxf(ua.y + bfhi(vv.x), 0.f));
                w.y = pk2(fmaxf(ua.z + bflo(vv.y), 0.f), fmaxf(ua.w + bfhi(vv.y), 0.f));
                w.z = pk2(fmaxf(ub.x + bflo(vv.z), 0.f), fmaxf(ub.y + bfhi(vv.z), 0.f));
                w.w = pk2(fmaxf(ub.z + bflo(vv.w), 0.f), fmaxf(ub.w + bfhi(vv.w), 0.f));
            } else {
                w = (uint4){0u, 0u, 0u, 0u};
            }
            *(uint4*)&hs[cur][r * HP + kk] = w;
        }

        // (5) stage next tile's CSR metadata into the other buffer
        if (hn && tid < TR) { srcA[cur ^ 1][tid] = nsrc; slotB[cur ^ 1][tid] = nsl; }

        // (6) single barrier per tile
        __syncthreads();
        ssp0 = ssc0; ssp1 = ssc1; prevbuf = cur;
    }
    if (ntile > 0) mfma_tile(prevbuf, ssp0, ssp1);
    __syncthreads();

    for (int idx = tid; idx < 16 * F; idx += BLOCK) {
        int sl = idx / F, cc = idx % F;
        float m = decf(accs[sl * ACCSTR + cc]);
        float o = isfinite(m) ? (m + B2[cc]) : 0.f;   // empty segment -> 0
        Y[(size_t)(n0 + sl) * F + cc] = o;
    }
}

// ============================ global max-pool + FC ============================
__global__ void k_pool(const float* __restrict__ X3, const int* __restrict__ batch,
                       unsigned* poolEnc) {
    int gph = blockIdx.x;
    int seg = blockIdx.y;
    int c = threadIdx.x;
    int lo = 0, hi = NNODES;
    while (lo < hi) { int mid = (lo + hi) >> 1; if (batch[mid] < gph) lo = mid + 1; else hi = mid; }
    int start = lo;
    hi = NNODES;
    while (lo < hi) { int mid = (lo + hi) >> 1; if (batch[mid] < gph + 1) lo = mid + 1; else hi = mid; }
    int end = lo;
    int chunk = (end - start + 7) >> 3;
    int s = start + seg * chunk;
    int e = min(end, s + chunk);
    float m = -INFINITY;
    for (int n = s; n < e; n++) m = fmaxf(m, X3[(size_t)n * 256 + c]);
    atomicMax(&poolEnc[gph * 256 + c], encf(m));
}

__global__ __launch_bounds__(128) void k_fc(const unsigned* __restrict__ poolEnc,
                                            const float* __restrict__ Wfc,
                                            const float* __restrict__ Bfc,
                                            float* __restrict__ out) {
    __shared__ float p[256];
    int gph = blockIdx.x, c = threadIdx.x;
    for (int k = c; k < 256; k += 128) {
        float m = decf(poolEnc[gph * 256 + k]);
        p[k] = isfinite(m) ? m : 0.f;
    }
    __syncthreads();
    float s = Bfc[c];
    for (int k = 0; k < 256; k++) s += p[k] * Wfc[k * 128 + c];
    out[gph * 128 + c] = s;
}

// ============================ launch ============================
extern "C" void kernel_launch(void* const* d_in, const int* in_sizes, int n_in,
                              void* d_out, int out_size, void* d_ws, size_t ws_size,
                              hipStream_t stream) {
    const float* x     = (const float*)d_in[0];
    const int*   ei    = (const int*)d_in[1];
    const int*   batch = (const int*)d_in[2];
    const float* w1_1 = (const float*)d_in[3];
    const float* b1_1 = (const float*)d_in[4];
    const float* w2_1 = (const float*)d_in[5];
    const float* b2_1 = (const float*)d_in[6];
    const float* w1_2 = (const float*)d_in[7];
    const float* b1_2 = (const float*)d_in[8];
    const float* w2_2 = (const float*)d_in[9];
    const float* b2_2 = (const float*)d_in[10];
    const float* w1_3 = (const float*)d_in[11];
    const float* b1_3 = (const float*)d_in[12];
    const float* w2_3 = (const float*)d_in[13];
    const float* b2_3 = (const float*)d_in[14];
    const float* wfc  = (const float*)d_in[15];
    const float* bfc  = (const float*)d_in[16];
    float* out = (float*)d_out;

    char* ws = (char*)d_ws;
    size_t off = 0;
    auto alloc = [&](size_t bytes) {
        void* p = ws + off;
        off = (off + bytes + 255) & ~(size_t)255;
        return p;
    };
    int* deg      = (int*)alloc((size_t)NNODES * 4);
    int* cursor   = (int*)alloc((size_t)NNODES * 4);
    int* rowptr   = (int*)alloc((size_t)(NNODES + 1) * 4);
    int* bsum     = (int*)alloc(256 * 4);
    int* boff     = (int*)alloc(256 * 4);
    int* csr_src  = (int*)alloc((size_t)NEDGES * 4);
    int* csr_dst  = (int*)alloc((size_t)NEDGES * 4);
    float* U      = (float*)alloc((size_t)NNODES * 256 * 4);
    unsigned short* V = (unsigned short*)alloc((size_t)NNODES * 256 * 2);
    float* x1     = (float*)alloc((size_t)NNODES * 64 * 4);
    float* x2     = (float*)alloc((size_t)NNODES * 128 * 4);
    float* x3     = (float*)alloc((size_t)NNODES * 256 * 4);
    unsigned* poolEnc = (unsigned*)alloc((size_t)NGRAPHS * 256 * 4);
    (void)ws_size; (void)in_sizes; (void)n_in; (void)out_size;

    // CSR by dst (shared across the 3 layers)
    k_init<<<256, 256, 0, stream>>>(deg, cursor, poolEnc);
    k_count<<<NEDGES / 256, 256, 0, stream>>>(ei, deg);
    k_scan1<<<256, 256, 0, stream>>>(deg, rowptr, bsum);
    k_scan2<<<1, 256, 0, stream>>>(bsum, boff);
    k_scan3<<<256, 256, 0, stream>>>(rowptr, boff);
    k_scatter<<<NEDGES / 256, 256, 0, stream>>>(ei, rowptr, cursor, csr_src, csr_dst);

    // layer 1: F_in=3, H=64, F=64   (scalar k_uv; FIN=3 has no MFMA fit)
    k_uv<3, 64><<<NNODES / 16, 256, 0, stream>>>(x, w1_1, b1_1, U, V);
    k_agg<64, 64, 2, 2><<<NNODES / 16, 256, 0, stream>>>(U, V, w2_1, b2_1, rowptr, csr_src, csr_dst, x1);
    // layer 2: F_in=64, H=128 — split-precision MFMA k_uv (8 waves, 256 blocks)
    k_uv_mfma<64, 128><<<NNODES / 256, 512, 0, stream>>>(x1, w1_2, b1_2, U, V);
    k_agg<128, 128, 1, 8><<<NNODES / 16, 512, 0, stream>>>(U, V, w2_2, b2_2, rowptr, csr_src, csr_dst, x2);
    // layer 3: F_in=128, H=256 — split-precision MFMA k_uv (16 waves, 256 blocks)
    k_uv_mfma<128, 256><<<NNODES / 256, 1024, 0, stream>>>(x2, w1_3, b1_3, U, V);
    k_agg<256, 256, 1, 16><<<NNODES / 16, 1024, 0, stream>>>(U, V, w2_3, b2_3, rowptr, csr_src, csr_dst, x3);

    // global max pool + FC
    k_pool<<<dim3(NGRAPHS, 8), 256, 0, stream>>>(x3, batch, poolEnc);
    k_fc<<<NGRAPHS, 128, 0, stream>>>(poolEnc, wfc, bfc, out);
}

// Round 13
// 751.466 us; speedup vs baseline: 1.2720x; 1.0446x over previous
//
#include <hip/hip_runtime.h>
#include <hip/hip_bf16.h>
#include <math.h>

#define NNODES 65536
#define NEDGES 1048576
#define NGRAPHS 64

typedef __attribute__((ext_vector_type(8))) short short8;
typedef __attribute__((ext_vector_type(4))) float f32x4;

// ---- order-preserving float<->uint encoding for atomicMax-based max ----
__device__ __forceinline__ unsigned encf(float f) {
    unsigned u = __float_as_uint(f);
    return (u & 0x80000000u) ? ~u : (u | 0x80000000u);
}
__device__ __forceinline__ float decf(unsigned u) {
    unsigned v = (u & 0x80000000u) ? (u & 0x7FFFFFFFu) : ~u;
    return __uint_as_float(v);
}
#define ENC_NEG_INF 0x007FFFFFu   // encf(-inf)

// RNE float -> bf16 bits (finite values only)
__device__ __forceinline__ unsigned bfbits(float f) {
    unsigned u = __float_as_uint(f);
    return (u + 0x7FFFu + ((u >> 16) & 1u)) >> 16;
}
__device__ __forceinline__ float bfval(unsigned bits) { return __uint_as_float(bits << 16); }
// HOT path: HW packed RNE convert (1 VALU op / 2 elems). Round-8 lesson:
// __float2bfloat16 is NOT RNE on this toolchain; v_cvt_pk_bf16_f32 is RNE
// in HW and matches bfbits (verified passing rounds 10-12).
__device__ __forceinline__ unsigned pk2(float a, float b) {
    unsigned r;
    asm("v_cvt_pk_bf16_f32 %0, %1, %2" : "=v"(r) : "v"(a), "v"(b));
    return r;   // a -> low 16, b -> high 16
}
__device__ __forceinline__ float bflo(unsigned p) { return __uint_as_float(p << 16); }
__device__ __forceinline__ float bfhi(unsigned p) { return __uint_as_float(p & 0xFFFF0000u); }

// ============================ CSR build ============================
__global__ void k_init(int* deg, int* cursor, unsigned* poolEnc) {
    int i = blockIdx.x * 256 + threadIdx.x;
    if (i < NNODES) { deg[i] = 0; cursor[i] = 0; }
    if (i < NGRAPHS * 256) poolEnc[i] = ENC_NEG_INF;
}

__global__ void k_count(const int* __restrict__ ei, int* deg) {
    int e = blockIdx.x * 256 + threadIdx.x;
    atomicAdd(&deg[ei[NEDGES + e]], 1);
}

__global__ void k_scan1(const int* __restrict__ deg, int* rowptr, int* bsum) {
    __shared__ int s[256];
    int t = threadIdx.x, b = blockIdx.x;
    int v = deg[b * 256 + t];
    s[t] = v;
    __syncthreads();
    for (int off = 1; off < 256; off <<= 1) {
        int x = (t >= off) ? s[t - off] : 0;
        __syncthreads();
        if (t >= off) s[t] += x;
        __syncthreads();
    }
    rowptr[b * 256 + t] = s[t] - v;       // local exclusive
    if (t == 255) bsum[b] = s[255];
}

__global__ void k_scan2(const int* __restrict__ bsum, int* boff) {
    __shared__ int s[256];
    int t = threadIdx.x;
    int v = bsum[t];
    s[t] = v;
    __syncthreads();
    for (int off = 1; off < 256; off <<= 1) {
        int x = (t >= off) ? s[t - off] : 0;
        __syncthreads();
        if (t >= off) s[t] += x;
        __syncthreads();
    }
    boff[t] = s[t] - v;                   // exclusive block offsets
}

__global__ void k_scan3(int* rowptr, const int* __restrict__ boff) {
    int i = blockIdx.x * 256 + threadIdx.x;
    rowptr[i] += boff[blockIdx.x];
    if (i == 0) rowptr[NNODES] = NEDGES;
}

__global__ void k_scatter(const int* __restrict__ ei, const int* __restrict__ rowptr,
                          int* cursor, int* csr_src, int* csr_dst) {
    int e = blockIdx.x * 256 + threadIdx.x;
    int s = ei[e], d = ei[NEDGES + e];
    int pos = rowptr[d] + atomicAdd(&cursor[d], 1);
    csr_src[pos] = s;
    csr_dst[pos] = d;
}

// ============================ U/V precompute ============================
// U[i] = X[i] @ (W1_top - W1_bot) + b1  (fp32, dst-local, L1-cached in k_agg)
// V[i] = X[i] @ W1_bot                  (bf16: the random-gathered operand)
// Scalar VALU version — kept for layer 1 only (FIN=3: no MFMA fit).
template <int FIN, int H>
__global__ __launch_bounds__(256) void k_uv(const float* __restrict__ X,
                                            const float* __restrict__ W1,
                                            const float* __restrict__ B1,
                                            float* __restrict__ U,
                                            unsigned short* __restrict__ Vb) {
    constexpr int NPT = (16 * H) / 256;   // nodes per thread
    __shared__ float xs[16][FIN];
    int tid = threadIdx.x;
    int n0 = blockIdx.x * 16;
    for (int idx = tid; idx < 16 * FIN; idx += 256)
        xs[idx / FIN][idx % FIN] = X[(size_t)(n0 + idx / FIN) * FIN + (idx % FIN)];
    __syncthreads();
    int h = tid & (H - 1);
    int nb = (tid / H) * NPT;
    float u[NPT], v[NPT];
    float bb = B1[h];
#pragma unroll
    for (int n = 0; n < NPT; n++) { u[n] = bb; v[n] = 0.f; }
    for (int f = 0; f < FIN; f++) {
        float wt = W1[f * H + h];
        float wb = W1[(FIN + f) * H + h];
        float wd = wt - wb;
#pragma unroll
        for (int n = 0; n < NPT; n++) {
            float xv = xs[nb + n][f];
            u[n] += xv * wd;
            v[n] += xv * wb;
        }
    }
#pragma unroll
    for (int n = 0; n < NPT; n++) {
        U[(size_t)(n0 + nb + n) * H + h] = u[n];
        Vb[(size_t)(n0 + nb + n) * H + h] = (unsigned short)bfbits(v[n]);
    }
}

// ==================== U/V precompute via MFMA (layers 2,3) ====================
// Split precision: X and W each split into bf16 hi+lo; S = Xhi@Whi + Xhi@Wlo
// + Xlo@Whi (fp32 accum) -> ~2^-18 relative error (== fp32-path accuracy).
// Fragment layouts mirror the verified k_agg [m89]. Verified round 12.
template <int FIN, int H>
__global__ __launch_bounds__((H / 16) * 64)
void k_uv_mfma(const float* __restrict__ X,
               const float* __restrict__ W1,
               const float* __restrict__ B1,
               float* __restrict__ U,
               unsigned short* __restrict__ Vb) {
    constexpr int WAVES = H / 16;
    constexpr int BLOCK = WAVES * 64;
    constexpr int KS = FIN / 32;          // k-steps
    constexpr int NPB = 16;               // node-tiles (of 16) per block
    constexpr int FP = FIN + 8;           // padded LDS row (bf16 units)
    static_assert(FIN % 32 == 0 && (16 * FIN) % (2 * BLOCK) == 0, "shape");

    __shared__ unsigned short xhi[16 * FP];
    __shared__ unsigned short xlo[16 * FP];

    int tid = threadIdx.x;
    int ln = tid & 15;
    int qd = (tid >> 4) & 3;
    int wv = tid >> 6;
    int col = wv * 16 + ln;

    // ---- W fragment planes (bf16 hi/lo, top & bottom halves), once ----
    short8 bth[KS], btl[KS], bbh[KS], bbl[KS];
#pragma unroll
    for (int ks = 0; ks < KS; ks++) {
        int kb = ks * 32 + qd * 8;
        short8 th, tl, bh, bl;
#pragma unroll
        for (int j = 0; j < 8; j++) {
            float wt = W1[(size_t)(kb + j) * H + col];
            float wb = W1[(size_t)(FIN + kb + j) * H + col];
            unsigned thb = bfbits(wt), bhb = bfbits(wb);
            th[j] = (short)thb;
            bh[j] = (short)bhb;
            tl[j] = (short)bfbits(wt - bfval(thb));
            bl[j] = (short)bfbits(wb - bfval(bhb));
        }
        bth[ks] = th; btl[ks] = tl; bbh[ks] = bh; bbl[ks] = bl;
    }

    float bias = B1[col];
    int nbase0 = blockIdx.x * (NPB * 16);

    // staging assignment: 2 consecutive floats per thread
    int sidx = tid * 2;
    int snode = sidx / FIN;               // 0..15
    int sf = sidx % FIN;

    float2 xr = *(const float2*)&X[(size_t)(nbase0 + snode) * FIN + sf];

    for (int t = 0; t < NPB; t++) {
        // write tile t into LDS as hi/lo bf16 planes
        unsigned h0 = bfbits(xr.x), h1 = bfbits(xr.y);
        unsigned l0 = bfbits(xr.x - bfval(h0));
        unsigned l1 = bfbits(xr.y - bfval(h1));
        *(unsigned*)&xhi[snode * FP + sf] = h0 | (h1 << 16);
        *(unsigned*)&xlo[snode * FP + sf] = l0 | (l1 << 16);
        // prefetch tile t+1 (latency hides under MFMA phase)
        if (t + 1 < NPB)
            xr = *(const float2*)&X[(size_t)(nbase0 + (t + 1) * 16 + snode) * FIN + sf];
        __syncthreads();

        f32x4 at = (f32x4){0.f, 0.f, 0.f, 0.f};
        f32x4 ab = (f32x4){0.f, 0.f, 0.f, 0.f};
#pragma unroll
        for (int ks = 0; ks < KS; ks++) {
            int ko = ks * 32 + qd * 8;
            short8 ah = *(const short8*)&xhi[ln * FP + ko];
            short8 al = *(const short8*)&xlo[ln * FP + ko];
            at = __builtin_amdgcn_mfma_f32_16x16x32_bf16(ah, bth[ks], at, 0, 0, 0);
            at = __builtin_amdgcn_mfma_f32_16x16x32_bf16(ah, btl[ks], at, 0, 0, 0);
            at = __builtin_amdgcn_mfma_f32_16x16x32_bf16(al, bth[ks], at, 0, 0, 0);
            ab = __builtin_amdgcn_mfma_f32_16x16x32_bf16(ah, bbh[ks], ab, 0, 0, 0);
            ab = __builtin_amdgcn_mfma_f32_16x16x32_bf16(ah, bbl[ks], ab, 0, 0, 0);
            ab = __builtin_amdgcn_mfma_f32_16x16x32_bf16(al, bbh[ks], ab, 0, 0, 0);
        }

        int nb = nbase0 + t * 16 + qd * 4;
#pragma unroll
        for (int j = 0; j < 4; j++) {
            U[(size_t)(nb + j) * H + col] = at[j] - ab[j] + bias;   // X@(Wt-Wb)+b
            Vb[(size_t)(nb + j) * H + col] = (unsigned short)bfbits(ab[j]); // X@Wb
        }
        __syncthreads();   // tile consumed before next overwrite
    }
}

// ================= fused edge-GEMM (MFMA bf16) + segment-max =================
// Block owns NPG dst nodes + all their in-edges (CSR) -> no global atomics.
// Round-5 pipeline (verified best) + pk2 asm. Round-13: NPG=32 (was 16) —
// per-block overheads (W2 slice re-read: 256KB/block through L2, Bf-load,
// epilogue, final-tile pad waste) all scale with BLOCK COUNT, not edge
// count; halving blocks halves them. Slots still fit signed char.
template <int H, int F, int RWAVES, int CWAVES, int NPG>
__global__ __launch_bounds__(RWAVES * CWAVES * 64)
void k_agg(const float* __restrict__ U,
           const unsigned short* __restrict__ Vb,
           const float* __restrict__ W2,
           const float* __restrict__ B2,
           const int* __restrict__ rowptr,
           const int* __restrict__ csr_src,
           const int* __restrict__ csr_dst,
           float* __restrict__ Y) {
    constexpr int BLOCK = RWAVES * CWAVES * 64;
    constexpr int TR = 32 * RWAVES;         // edge rows per tile
    constexpr int HP = H + 8;               // padded row (bf16 units), 16B-aligned frags
    constexpr int CPW = F / CWAVES;         // cols per wave
    constexpr int NT = CPW / 16;            // n-tiles per wave
    constexpr int KS = H / 32;              // k-steps
    constexpr int ACCSTR = F + 1;           // bank-spread accumulator stride
    constexpr int LPR = H / 8;              // threads per hidden row (8 elems each)
    constexpr int RPP = BLOCK / LPR;        // rows per construction pass
    constexpr int NPASS = TR / RPP;         // construction passes per tile
    static_assert(H % 32 == 0 && NT >= 1 && RPP >= 1 && TR % RPP == 0, "shape");
    static_assert(NPG <= 120, "slot fits signed char");

    __shared__ unsigned short hs[2][TR * HP];   // double-buffered hidden tile
    __shared__ unsigned accs[NPG * ACCSTR];     // per-slot running max (encoded)
    __shared__ int srcA[2][TR];
    __shared__ __align__(4) signed char slotB[2][TR];

    int tid = threadIdx.x;
    int n0 = blockIdx.x * NPG;

    int ln = tid & 15;              // MFMA n/m lane index
    int qd = (tid >> 4) & 3;        // MFMA quad
    int wv = tid >> 6;
    int rw = wv / CWAVES;           // row group
    int cw = wv % CWAVES;           // col wave

    // ---- load W2 fragments into registers (bf16), once ----
    short8 Bf[NT][KS];
#pragma unroll
    for (int nt = 0; nt < NT; nt++) {
        int col = cw * CPW + nt * 16 + ln;
#pragma unroll
        for (int ks = 0; ks < KS; ks++) {
            int kb = ks * 32 + qd * 8;
            short8 b;
#pragma unroll
            for (int j = 0; j < 8; j++)
                b[j] = (short)bfbits(W2[(size_t)(kb + j) * F + col]);
            Bf[nt][ks] = b;
        }
    }

    for (int idx = tid; idx < NPG * ACCSTR; idx += BLOCK) accs[idx] = ENC_NEG_INF;

    int e0 = rowptr[n0], e1 = rowptr[n0 + NPG];
    int ntile = (e1 - e0 + TR - 1) / TR;

    int rid = tid / LPR;            // construction: my row within a pass
    int kk = (tid % LPR) * 8;       // construction: my 8-elem chunk

    // stage CSR metadata for tile 0
    if (tid < TR) {
        int p = e0 + tid;
        int s = 0; signed char sl = -1;
        if (p < e1) { s = csr_src[p]; sl = (signed char)(csr_dst[p] - n0); }
        srcA[0][tid] = s; slotB[0][tid] = sl;
    }
    __syncthreads();

    // MFMA + segmented-max for one completed tile (reads hs[buf])
    auto mfma_tile = [&](int buf, char4 s0, char4 s1) {
        f32x4 acc[2][NT];
#pragma unroll
        for (int mt = 0; mt < 2; mt++)
#pragma unroll
            for (int nt = 0; nt < NT; nt++)
                acc[mt][nt] = (f32x4){0.f, 0.f, 0.f, 0.f};

#pragma unroll
        for (int ks = 0; ks < KS; ks++) {
            int ko = ks * 32 + qd * 8;
            short8 a0 = *(const short8*)&hs[buf][(rw * 32 + ln) * HP + ko];
            short8 a1 = *(const short8*)&hs[buf][(rw * 32 + 16 + ln) * HP + ko];
#pragma unroll
            for (int nt = 0; nt < NT; nt++) {
                acc[0][nt] = __builtin_amdgcn_mfma_f32_16x16x32_bf16(a0, Bf[nt][ks], acc[0][nt], 0, 0, 0);
                acc[1][nt] = __builtin_amdgcn_mfma_f32_16x16x32_bf16(a1, Bf[nt][ks], acc[1][nt], 0, 0, 0);
            }
        }

#pragma unroll
        for (int mt = 0; mt < 2; mt++) {
            char4 ss = mt ? s1 : s0;
#pragma unroll
            for (int nt = 0; nt < NT; nt++) {
                int colw = cw * CPW + nt * 16 + ln;
                float c0 = acc[mt][nt][0], c1 = acc[mt][nt][1];
                float c2 = acc[mt][nt][2], c3 = acc[mt][nt][3];
                float m3 = c3;
                float m2 = (ss.z == ss.w) ? fmaxf(c2, m3) : c2;
                float m1 = (ss.y == ss.z) ? fmaxf(c1, m2) : c1;
                float m0 = (ss.x == ss.y) ? fmaxf(c0, m1) : c0;
                if (ss.x >= 0)                 atomicMax(&accs[(int)ss.x * ACCSTR + colw], encf(m0));
                if (ss.y >= 0 && ss.y != ss.x) atomicMax(&accs[(int)ss.y * ACCSTR + colw], encf(m1));
                if (ss.z >= 0 && ss.z != ss.y) atomicMax(&accs[(int)ss.z * ACCSTR + colw], encf(m2));
                if (ss.w >= 0 && ss.w != ss.z) atomicMax(&accs[(int)ss.w * ACCSTR + colw], encf(m3));
            }
        }
    };

    char4 ssp0 = make_char4(-1, -1, -1, -1), ssp1 = make_char4(-1, -1, -1, -1);
    int prevbuf = 0;

    for (int t = 0; t < ntile; t++) {
        int cur = t & 1;

        // (1) capture tile-t metadata; issue gathered-V loads EARLY
        int msrc[NPASS]; int msl[NPASS];
#pragma unroll
        for (int ps = 0; ps < NPASS; ps++) {
            int r = ps * RPP + rid;
            msrc[ps] = srcA[cur][r];
            msl[ps] = slotB[cur][r];
        }
        uint4 vreg[NPASS];
#pragma unroll
        for (int ps = 0; ps < NPASS; ps++)
            vreg[ps] = *(const uint4*)&Vb[(size_t)msrc[ps] * H + kk];   // src=0 for pad rows: safe
        char4 ssc0 = *(const char4*)&slotB[cur][rw * 32 + qd * 4];
        char4 ssc1 = *(const char4*)&slotB[cur][rw * 32 + 16 + qd * 4];

        // (2) prefetch CSR metadata for tile t+1 into registers
        int nsrc = 0; signed char nsl = -1;
        bool hn = (t + 1 < ntile);
        if (hn && tid < TR) {
            int p = e0 + (t + 1) * TR + tid;
            if (p < e1) { nsrc = csr_src[p]; nsl = (signed char)(csr_dst[p] - n0); }
        }

        // (3) MFMA + seg-max for tile t-1 — hides the V-gather latency
        if (t > 0) mfma_tile(prevbuf, ssp0, ssp1);

        // (4) build hidden tile t: hs = bf16(relu(U[dst] + V[src]))
#pragma unroll
        for (int ps = 0; ps < NPASS; ps++) {
            int r = ps * RPP + rid;
            uint4 w;
            if (msl[ps] >= 0) {
                const float4 ua = *(const float4*)&U[(size_t)(n0 + msl[ps]) * H + kk];
                const float4 ub = *(const float4*)&U[(size_t)(n0 + msl[ps]) * H + kk + 4];
                const uint4 vv = vreg[ps];
                w.x = pk2(fmaxf(ua.x + bflo(vv.x), 0.f), fmaxf(ua.y + bfhi(vv.x), 0.f));
                w.y = pk2(fmaxf(ua.z + bflo(vv.y), 0.f), fmaxf(ua.w + bfhi(vv.y), 0.f));
                w.z = pk2(fmaxf(ub.x + bflo(vv.z), 0.f), fmaxf(ub.y + bfhi(vv.z), 0.f));
                w.w = pk2(fmaxf(ub.z + bflo(vv.w), 0.f), fmaxf(ub.w + bfhi(vv.w), 0.f));
            } else {
                w = (uint4){0u, 0u, 0u, 0u};
            }
            *(uint4*)&hs[cur][r * HP + kk] = w;
        }

        // (5) stage next tile's CSR metadata into the other buffer
        if (hn && tid < TR) { srcA[cur ^ 1][tid] = nsrc; slotB[cur ^ 1][tid] = nsl; }

        // (6) single barrier per tile
        __syncthreads();
        ssp0 = ssc0; ssp1 = ssc1; prevbuf = cur;
    }
    if (ntile > 0) mfma_tile(prevbuf, ssp0, ssp1);
    __syncthreads();

    for (int idx = tid; idx < NPG * F; idx += BLOCK) {
        int sl = idx / F, cc = idx % F;
        float m = decf(accs[sl * ACCSTR + cc]);
        float o = isfinite(m) ? (m + B2[cc]) : 0.f;   // empty segment -> 0
        Y[(size_t)(n0 + sl) * F + cc] = o;
    }
}

// ============================ global max-pool + FC ============================
__global__ void k_pool(const float* __restrict__ X3, const int* __restrict__ batch,
                       unsigned* poolEnc) {
    int gph = blockIdx.x;
    int seg = blockIdx.y;
    int c = threadIdx.x;
    int lo = 0, hi = NNODES;
    while (lo < hi) { int mid = (lo + hi) >> 1; if (batch[mid] < gph) lo = mid + 1; else hi = mid; }
    int start = lo;
    hi = NNODES;
    while (lo < hi) { int mid = (lo + hi) >> 1; if (batch[mid] < gph + 1) lo = mid + 1; else hi = mid; }
    int end = lo;
    int chunk = (end - start + 7) >> 3;
    int s = start + seg * chunk;
    int e = min(end, s + chunk);
    float m = -INFINITY;
    for (int n = s; n < e; n++) m = fmaxf(m, X3[(size_t)n * 256 + c]);
    atomicMax(&poolEnc[gph * 256 + c], encf(m));
}

__global__ __launch_bounds__(128) void k_fc(const unsigned* __restrict__ poolEnc,
                                            const float* __restrict__ Wfc,
                                            const float* __restrict__ Bfc,
                                            float* __restrict__ out) {
    __shared__ float p[256];
    int gph = blockIdx.x, c = threadIdx.x;
    for (int k = c; k < 256; k += 128) {
        float m = decf(poolEnc[gph * 256 + k]);
        p[k] = isfinite(m) ? m : 0.f;
    }
    __syncthreads();
    float s = Bfc[c];
    for (int k = 0; k < 256; k++) s += p[k] * Wfc[k * 128 + c];
    out[gph * 128 + c] = s;
}

// ============================ launch ============================
extern "C" void kernel_launch(void* const* d_in, const int* in_sizes, int n_in,
                              void* d_out, int out_size, void* d_ws, size_t ws_size,
                              hipStream_t stream) {
    const float* x     = (const float*)d_in[0];
    const int*   ei    = (const int*)d_in[1];
    const int*   batch = (const int*)d_in[2];
    const float* w1_1 = (const float*)d_in[3];
    const float* b1_1 = (const float*)d_in[4];
    const float* w2_1 = (const float*)d_in[5];
    const float* b2_1 = (const float*)d_in[6];
    const float* w1_2 = (const float*)d_in[7];
    const float* b1_2 = (const float*)d_in[8];
    const float* w2_2 = (const float*)d_in[9];
    const float* b2_2 = (const float*)d_in[10];
    const float* w1_3 = (const float*)d_in[11];
    const float* b1_3 = (const float*)d_in[12];
    const float* w2_3 = (const float*)d_in[13];
    const float* b2_3 = (const float*)d_in[14];
    const float* wfc  = (const float*)d_in[15];
    const float* bfc  = (const float*)d_in[16];
    float* out = (float*)d_out;

    char* ws = (char*)d_ws;
    size_t off = 0;
    auto alloc = [&](size_t bytes) {
        void* p = ws + off;
        off = (off + bytes + 255) & ~(size_t)255;
        return p;
    };
    int* deg      = (int*)alloc((size_t)NNODES * 4);
    int* cursor   = (int*)alloc((size_t)NNODES * 4);
    int* rowptr   = (int*)alloc((size_t)(NNODES + 1) * 4);
    int* bsum     = (int*)alloc(256 * 4);
    int* boff     = (int*)alloc(256 * 4);
    int* csr_src  = (int*)alloc((size_t)NEDGES * 4);
    int* csr_dst  = (int*)alloc((size_t)NEDGES * 4);
    float* U      = (float*)alloc((size_t)NNODES * 256 * 4);
    unsigned short* V = (unsigned short*)alloc((size_t)NNODES * 256 * 2);
    float* x1     = (float*)alloc((size_t)NNODES * 64 * 4);
    float* x2     = (float*)alloc((size_t)NNODES * 128 * 4);
    float* x3     = (float*)alloc((size_t)NNODES * 256 * 4);
    unsigned* poolEnc = (unsigned*)alloc((size_t)NGRAPHS * 256 * 4);
    (void)ws_size; (void)in_sizes; (void)n_in; (void)out_size;

    // CSR by dst (shared across the 3 layers)
    k_init<<<256, 256, 0, stream>>>(deg, cursor, poolEnc);
    k_count<<<NEDGES / 256, 256, 0, stream>>>(ei, deg);
    k_scan1<<<256, 256, 0, stream>>>(deg, rowptr, bsum);
    k_scan2<<<1, 256, 0, stream>>>(bsum, boff);
    k_scan3<<<256, 256, 0, stream>>>(rowptr, boff);
    k_scatter<<<NEDGES / 256, 256, 0, stream>>>(ei, rowptr, cursor, csr_src, csr_dst);

    // layer 1: F_in=3, H=64, F=64   (scalar k_uv; NPG=32 -> 2048 blocks)
    k_uv<3, 64><<<NNODES / 16, 256, 0, stream>>>(x, w1_1, b1_1, U, V);
    k_agg<64, 64, 2, 2, 32><<<NNODES / 32, 256, 0, stream>>>(U, V, w2_1, b2_1, rowptr, csr_src, csr_dst, x1);
    // layer 2: F_in=64, H=128 — MFMA k_uv; k_agg 1x8 waves, NPG=32
    k_uv_mfma<64, 128><<<NNODES / 256, 512, 0, stream>>>(x1, w1_2, b1_2, U, V);
    k_agg<128, 128, 1, 8, 32><<<NNODES / 32, 512, 0, stream>>>(U, V, w2_2, b2_2, rowptr, csr_src, csr_dst, x2);
    // layer 3: F_in=128, H=256 — MFMA k_uv; k_agg 1x16 waves, NPG=32
    k_uv_mfma<128, 256><<<NNODES / 256, 1024, 0, stream>>>(x2, w1_3, b1_3, U, V);
    k_agg<256, 256, 1, 16, 32><<<NNODES / 32, 1024, 0, stream>>>(U, V, w2_3, b2_3, rowptr, csr_src, csr_dst, x3);

    // global max pool + FC
    k_pool<<<dim3(NGRAPHS, 8), 256, 0, stream>>>(x3, batch, poolEnc);
    k_fc<<<NGRAPHS, 128, 0, stream>>>(poolEnc, wfc, bfc, out);
}

// Round 14
// 733.157 us; speedup vs baseline: 1.3038x; 1.0250x over previous
//
#include <hip/hip_runtime.h>
#include <hip/hip_bf16.h>
#include <math.h>

#define NNODES 65536
#define NEDGES 1048576
#define NGRAPHS 64

typedef __attribute__((ext_vector_type(8))) short short8;
typedef __attribute__((ext_vector_type(4))) float f32x4;
typedef __attribute__((ext_vector_type(16))) float f32x16;

// ---- order-preserving float<->uint encoding for atomicMax-based max ----
__device__ __forceinline__ unsigned encf(float f) {
    unsigned u = __float_as_uint(f);
    return (u & 0x80000000u) ? ~u : (u | 0x80000000u);
}
__device__ __forceinline__ float decf(unsigned u) {
    unsigned v = (u & 0x80000000u) ? (u & 0x7FFFFFFFu) : ~u;
    return __uint_as_float(v);
}
#define ENC_NEG_INF 0x007FFFFFu   // encf(-inf)

// RNE float -> bf16 bits (finite values only)
__device__ __forceinline__ unsigned bfbits(float f) {
    unsigned u = __float_as_uint(f);
    return (u + 0x7FFFu + ((u >> 16) & 1u)) >> 16;
}
__device__ __forceinline__ float bfval(unsigned bits) { return __uint_as_float(bits << 16); }
// HOT path: HW packed RNE convert (1 VALU op / 2 elems). Round-8 lesson:
// __float2bfloat16 is NOT RNE on this toolchain; v_cvt_pk_bf16_f32 is RNE
// in HW and matches bfbits (verified passing rounds 10-13).
__device__ __forceinline__ unsigned pk2(float a, float b) {
    unsigned r;
    asm("v_cvt_pk_bf16_f32 %0, %1, %2" : "=v"(r) : "v"(a), "v"(b));
    return r;   // a -> low 16, b -> high 16
}
__device__ __forceinline__ float bflo(unsigned p) { return __uint_as_float(p << 16); }
__device__ __forceinline__ float bfhi(unsigned p) { return __uint_as_float(p & 0xFFFF0000u); }

// ============================ CSR build ============================
__global__ void k_init(int* deg, int* cursor, unsigned* poolEnc) {
    int i = blockIdx.x * 256 + threadIdx.x;
    if (i < NNODES) { deg[i] = 0; cursor[i] = 0; }
    if (i < NGRAPHS * 256) poolEnc[i] = ENC_NEG_INF;
}

__global__ void k_count(const int* __restrict__ ei, int* deg) {
    int e = blockIdx.x * 256 + threadIdx.x;
    atomicAdd(&deg[ei[NEDGES + e]], 1);
}

__global__ void k_scan1(const int* __restrict__ deg, int* rowptr, int* bsum) {
    __shared__ int s[256];
    int t = threadIdx.x, b = blockIdx.x;
    int v = deg[b * 256 + t];
    s[t] = v;
    __syncthreads();
    for (int off = 1; off < 256; off <<= 1) {
        int x = (t >= off) ? s[t - off] : 0;
        __syncthreads();
        if (t >= off) s[t] += x;
        __syncthreads();
    }
    rowptr[b * 256 + t] = s[t] - v;       // local exclusive
    if (t == 255) bsum[b] = s[255];
}

__global__ void k_scan2(const int* __restrict__ bsum, int* boff) {
    __shared__ int s[256];
    int t = threadIdx.x;
    int v = bsum[t];
    s[t] = v;
    __syncthreads();
    for (int off = 1; off < 256; off <<= 1) {
        int x = (t >= off) ? s[t - off] : 0;
        __syncthreads();
        if (t >= off) s[t] += x;
        __syncthreads();
    }
    boff[t] = s[t] - v;                   // exclusive block offsets
}

__global__ void k_scan3(int* rowptr, const int* __restrict__ boff) {
    int i = blockIdx.x * 256 + threadIdx.x;
    rowptr[i] += boff[blockIdx.x];
    if (i == 0) rowptr[NNODES] = NEDGES;
}

__global__ void k_scatter(const int* __restrict__ ei, const int* __restrict__ rowptr,
                          int* cursor, int* csr_src, int* csr_dst) {
    int e = blockIdx.x * 256 + threadIdx.x;
    int s = ei[e], d = ei[NEDGES + e];
    int pos = rowptr[d] + atomicAdd(&cursor[d], 1);
    csr_src[pos] = s;
    csr_dst[pos] = d;
}

// ============================ U/V precompute ============================
// Scalar VALU version — kept for layer 1 only (FIN=3: no MFMA fit).
template <int FIN, int H>
__global__ __launch_bounds__(256) void k_uv(const float* __restrict__ X,
                                            const float* __restrict__ W1,
                                            const float* __restrict__ B1,
                                            float* __restrict__ U,
                                            unsigned short* __restrict__ Vb) {
    constexpr int NPT = (16 * H) / 256;   // nodes per thread
    __shared__ float xs[16][FIN];
    int tid = threadIdx.x;
    int n0 = blockIdx.x * 16;
    for (int idx = tid; idx < 16 * FIN; idx += 256)
        xs[idx / FIN][idx % FIN] = X[(size_t)(n0 + idx / FIN) * FIN + (idx % FIN)];
    __syncthreads();
    int h = tid & (H - 1);
    int nb = (tid / H) * NPT;
    float u[NPT], v[NPT];
    float bb = B1[h];
#pragma unroll
    for (int n = 0; n < NPT; n++) { u[n] = bb; v[n] = 0.f; }
    for (int f = 0; f < FIN; f++) {
        float wt = W1[f * H + h];
        float wb = W1[(FIN + f) * H + h];
        float wd = wt - wb;
#pragma unroll
        for (int n = 0; n < NPT; n++) {
            float xv = xs[nb + n][f];
            u[n] += xv * wd;
            v[n] += xv * wb;
        }
    }
#pragma unroll
    for (int n = 0; n < NPT; n++) {
        U[(size_t)(n0 + nb + n) * H + h] = u[n];
        Vb[(size_t)(n0 + nb + n) * H + h] = (unsigned short)bfbits(v[n]);
    }
}

// ==================== U/V precompute via MFMA (layers 2,3) ====================
// Split precision (verified round 12): S = Xhi@Whi + Xhi@Wlo + Xlo@Whi.
template <int FIN, int H>
__global__ __launch_bounds__((H / 16) * 64)
void k_uv_mfma(const float* __restrict__ X,
               const float* __restrict__ W1,
               const float* __restrict__ B1,
               float* __restrict__ U,
               unsigned short* __restrict__ Vb) {
    constexpr int WAVES = H / 16;
    constexpr int BLOCK = WAVES * 64;
    constexpr int KS = FIN / 32;          // k-steps
    constexpr int NPB = 16;               // node-tiles (of 16) per block
    constexpr int FP = FIN + 8;           // padded LDS row (bf16 units)
    static_assert(FIN % 32 == 0 && (16 * FIN) % (2 * BLOCK) == 0, "shape");

    __shared__ unsigned short xhi[16 * FP];
    __shared__ unsigned short xlo[16 * FP];

    int tid = threadIdx.x;
    int ln = tid & 15;
    int qd = (tid >> 4) & 3;
    int wv = tid >> 6;
    int col = wv * 16 + ln;

    short8 bth[KS], btl[KS], bbh[KS], bbl[KS];
#pragma unroll
    for (int ks = 0; ks < KS; ks++) {
        int kb = ks * 32 + qd * 8;
        short8 th, tl, bh, bl;
#pragma unroll
        for (int j = 0; j < 8; j++) {
            float wt = W1[(size_t)(kb + j) * H + col];
            float wb = W1[(size_t)(FIN + kb + j) * H + col];
            unsigned thb = bfbits(wt), bhb = bfbits(wb);
            th[j] = (short)thb;
            bh[j] = (short)bhb;
            tl[j] = (short)bfbits(wt - bfval(thb));
            bl[j] = (short)bfbits(wb - bfval(bhb));
        }
        bth[ks] = th; btl[ks] = tl; bbh[ks] = bh; bbl[ks] = bl;
    }

    float bias = B1[col];
    int nbase0 = blockIdx.x * (NPB * 16);

    int sidx = tid * 2;
    int snode = sidx / FIN;               // 0..15
    int sf = sidx % FIN;

    float2 xr = *(const float2*)&X[(size_t)(nbase0 + snode) * FIN + sf];

    for (int t = 0; t < NPB; t++) {
        unsigned h0 = bfbits(xr.x), h1 = bfbits(xr.y);
        unsigned l0 = bfbits(xr.x - bfval(h0));
        unsigned l1 = bfbits(xr.y - bfval(h1));
        *(unsigned*)&xhi[snode * FP + sf] = h0 | (h1 << 16);
        *(unsigned*)&xlo[snode * FP + sf] = l0 | (l1 << 16);
        if (t + 1 < NPB)
            xr = *(const float2*)&X[(size_t)(nbase0 + (t + 1) * 16 + snode) * FIN + sf];
        __syncthreads();

        f32x4 at = (f32x4){0.f, 0.f, 0.f, 0.f};
        f32x4 ab = (f32x4){0.f, 0.f, 0.f, 0.f};
#pragma unroll
        for (int ks = 0; ks < KS; ks++) {
            int ko = ks * 32 + qd * 8;
            short8 ah = *(const short8*)&xhi[ln * FP + ko];
            short8 al = *(const short8*)&xlo[ln * FP + ko];
            at = __builtin_amdgcn_mfma_f32_16x16x32_bf16(ah, bth[ks], at, 0, 0, 0);
            at = __builtin_amdgcn_mfma_f32_16x16x32_bf16(ah, btl[ks], at, 0, 0, 0);
            at = __builtin_amdgcn_mfma_f32_16x16x32_bf16(al, bth[ks], at, 0, 0, 0);
            ab = __builtin_amdgcn_mfma_f32_16x16x32_bf16(ah, bbh[ks], ab, 0, 0, 0);
            ab = __builtin_amdgcn_mfma_f32_16x16x32_bf16(ah, bbl[ks], ab, 0, 0, 0);
            ab = __builtin_amdgcn_mfma_f32_16x16x32_bf16(al, bbh[ks], ab, 0, 0, 0);
        }

        int nb = nbase0 + t * 16 + qd * 4;
#pragma unroll
        for (int j = 0; j < 4; j++) {
            U[(size_t)(nb + j) * H + col] = at[j] - ab[j] + bias;   // X@(Wt-Wb)+b
            Vb[(size_t)(nb + j) * H + col] = (unsigned short)bfbits(ab[j]); // X@Wb
        }
        __syncthreads();   // tile consumed before next overwrite
    }
}

// ================= fused edge-GEMM (MFMA bf16 16x16) + segment-max =================
// Verified round-13 version — layers 1,2. Round-5 pipeline + pk2 asm + NPG.
template <int H, int F, int RWAVES, int CWAVES, int NPG>
__global__ __launch_bounds__(RWAVES * CWAVES * 64)
void k_agg(const float* __restrict__ U,
           const unsigned short* __restrict__ Vb,
           const float* __restrict__ W2,
           const float* __restrict__ B2,
           const int* __restrict__ rowptr,
           const int* __restrict__ csr_src,
           const int* __restrict__ csr_dst,
           float* __restrict__ Y) {
    constexpr int BLOCK = RWAVES * CWAVES * 64;
    constexpr int TR = 32 * RWAVES;         // edge rows per tile
    constexpr int HP = H + 8;               // padded row (bf16 units), 16B-aligned frags
    constexpr int CPW = F / CWAVES;         // cols per wave
    constexpr int NT = CPW / 16;            // n-tiles per wave
    constexpr int KS = H / 32;              // k-steps
    constexpr int ACCSTR = F + 1;           // bank-spread accumulator stride
    constexpr int LPR = H / 8;              // threads per hidden row (8 elems each)
    constexpr int RPP = BLOCK / LPR;        // rows per construction pass
    constexpr int NPASS = TR / RPP;         // construction passes per tile
    static_assert(H % 32 == 0 && NT >= 1 && RPP >= 1 && TR % RPP == 0, "shape");
    static_assert(NPG <= 120, "slot fits signed char");

    __shared__ unsigned short hs[2][TR * HP];   // double-buffered hidden tile
    __shared__ unsigned accs[NPG * ACCSTR];     // per-slot running max (encoded)
    __shared__ int srcA[2][TR];
    __shared__ __align__(4) signed char slotB[2][TR];

    int tid = threadIdx.x;
    int n0 = blockIdx.x * NPG;

    int ln = tid & 15;              // MFMA n/m lane index
    int qd = (tid >> 4) & 3;        // MFMA quad
    int wv = tid >> 6;
    int rw = wv / CWAVES;           // row group
    int cw = wv % CWAVES;           // col wave

    short8 Bf[NT][KS];
#pragma unroll
    for (int nt = 0; nt < NT; nt++) {
        int col = cw * CPW + nt * 16 + ln;
#pragma unroll
        for (int ks = 0; ks < KS; ks++) {
            int kb = ks * 32 + qd * 8;
            short8 b;
#pragma unroll
            for (int j = 0; j < 8; j++)
                b[j] = (short)bfbits(W2[(size_t)(kb + j) * F + col]);
            Bf[nt][ks] = b;
        }
    }

    for (int idx = tid; idx < NPG * ACCSTR; idx += BLOCK) accs[idx] = ENC_NEG_INF;

    int e0 = rowptr[n0], e1 = rowptr[n0 + NPG];
    int ntile = (e1 - e0 + TR - 1) / TR;

    int rid = tid / LPR;            // construction: my row within a pass
    int kk = (tid % LPR) * 8;       // construction: my 8-elem chunk

    if (tid < TR) {
        int p = e0 + tid;
        int s = 0; signed char sl = -1;
        if (p < e1) { s = csr_src[p]; sl = (signed char)(csr_dst[p] - n0); }
        srcA[0][tid] = s; slotB[0][tid] = sl;
    }
    __syncthreads();

    auto mfma_tile = [&](int buf, char4 s0, char4 s1) {
        f32x4 acc[2][NT];
#pragma unroll
        for (int mt = 0; mt < 2; mt++)
#pragma unroll
            for (int nt = 0; nt < NT; nt++)
                acc[mt][nt] = (f32x4){0.f, 0.f, 0.f, 0.f};

#pragma unroll
        for (int ks = 0; ks < KS; ks++) {
            int ko = ks * 32 + qd * 8;
            short8 a0 = *(const short8*)&hs[buf][(rw * 32 + ln) * HP + ko];
            short8 a1 = *(const short8*)&hs[buf][(rw * 32 + 16 + ln) * HP + ko];
#pragma unroll
            for (int nt = 0; nt < NT; nt++) {
                acc[0][nt] = __builtin_amdgcn_mfma_f32_16x16x32_bf16(a0, Bf[nt][ks], acc[0][nt], 0, 0, 0);
                acc[1][nt] = __builtin_amdgcn_mfma_f32_16x16x32_bf16(a1, Bf[nt][ks], acc[1][nt], 0, 0, 0);
            }
        }

#pragma unroll
        for (int mt = 0; mt < 2; mt++) {
            char4 ss = mt ? s1 : s0;
#pragma unroll
            for (int nt = 0; nt < NT; nt++) {
                int colw = cw * CPW + nt * 16 + ln;
                float c0 = acc[mt][nt][0], c1 = acc[mt][nt][1];
                float c2 = acc[mt][nt][2], c3 = acc[mt][nt][3];
                float m3 = c3;
                float m2 = (ss.z == ss.w) ? fmaxf(c2, m3) : c2;
                float m1 = (ss.y == ss.z) ? fmaxf(c1, m2) : c1;
                float m0 = (ss.x == ss.y) ? fmaxf(c0, m1) : c0;
                if (ss.x >= 0)                 atomicMax(&accs[(int)ss.x * ACCSTR + colw], encf(m0));
                if (ss.y >= 0 && ss.y != ss.x) atomicMax(&accs[(int)ss.y * ACCSTR + colw], encf(m1));
                if (ss.z >= 0 && ss.z != ss.y) atomicMax(&accs[(int)ss.z * ACCSTR + colw], encf(m2));
                if (ss.w >= 0 && ss.w != ss.z) atomicMax(&accs[(int)ss.w * ACCSTR + colw], encf(m3));
            }
        }
    };

    char4 ssp0 = make_char4(-1, -1, -1, -1), ssp1 = make_char4(-1, -1, -1, -1);
    int prevbuf = 0;

    for (int t = 0; t < ntile; t++) {
        int cur = t & 1;

        int msrc[NPASS]; int msl[NPASS];
#pragma unroll
        for (int ps = 0; ps < NPASS; ps++) {
            int r = ps * RPP + rid;
            msrc[ps] = srcA[cur][r];
            msl[ps] = slotB[cur][r];
        }
        uint4 vreg[NPASS];
#pragma unroll
        for (int ps = 0; ps < NPASS; ps++)
            vreg[ps] = *(const uint4*)&Vb[(size_t)msrc[ps] * H + kk];   // src=0 for pad rows: safe
        char4 ssc0 = *(const char4*)&slotB[cur][rw * 32 + qd * 4];
        char4 ssc1 = *(const char4*)&slotB[cur][rw * 32 + 16 + qd * 4];

        int nsrc = 0; signed char nsl = -1;
        bool hn = (t + 1 < ntile);
        if (hn && tid < TR) {
            int p = e0 + (t + 1) * TR + tid;
            if (p < e1) { nsrc = csr_src[p]; nsl = (signed char)(csr_dst[p] - n0); }
        }

        if (t > 0) mfma_tile(prevbuf, ssp0, ssp1);

#pragma unroll
        for (int ps = 0; ps < NPASS; ps++) {
            int r = ps * RPP + rid;
            uint4 w;
            if (msl[ps] >= 0) {
                const float4 ua = *(const float4*)&U[(size_t)(n0 + msl[ps]) * H + kk];
                const float4 ub = *(const float4*)&U[(size_t)(n0 + msl[ps]) * H + kk + 4];
                const uint4 vv = vreg[ps];
                w.x = pk2(fmaxf(ua.x + bflo(vv.x), 0.f), fmaxf(ua.y + bfhi(vv.x), 0.f));
                w.y = pk2(fmaxf(ua.z + bflo(vv.y), 0.f), fmaxf(ua.w + bfhi(vv.y), 0.f));
                w.z = pk2(fmaxf(ub.x + bflo(vv.z), 0.f), fmaxf(ub.y + bfhi(vv.z), 0.f));
                w.w = pk2(fmaxf(ub.z + bflo(vv.w), 0.f), fmaxf(ub.w + bfhi(vv.w), 0.f));
            } else {
                w = (uint4){0u, 0u, 0u, 0u};
            }
            *(uint4*)&hs[cur][r * HP + kk] = w;
        }

        if (hn && tid < TR) { srcA[cur ^ 1][tid] = nsrc; slotB[cur ^ 1][tid] = nsl; }

        __syncthreads();
        ssp0 = ssc0; ssp1 = ssc1; prevbuf = cur;
    }
    if (ntile > 0) mfma_tile(prevbuf, ssp0, ssp1);
    __syncthreads();

    for (int idx = tid; idx < NPG * F; idx += BLOCK) {
        int sl = idx / F, cc = idx % F;
        float m = decf(accs[sl * ACCSTR + cc]);
        float o = isfinite(m) ? (m + B2[cc]) : 0.f;   // empty segment -> 0
        Y[(size_t)(n0 + sl) * F + cc] = o;
    }
}

// ============ fused edge-GEMM (MFMA bf16 32x32) + segment-max — layer 3 ============
// Same pipeline, but 32x32x16 MFMA: one 32-col tile per wave costs the same
// B-regs per k (4/16k) but DOUBLE the flops per A-byte -> A-read redundancy
// F/32 instead of F/16 (the dominant LDS term halves). Unified regs:
// Bf 64 + acc 16 + arch ~45 ~= 125 <= 128 cap (round-6's NT=2 was ~144).
// C/D layout (m74/m101 verified): col=lane&31, row=(reg&3)+8*(reg>>2)+4*(lane>>5).
// A: [row=lane&31][k=kh*8+j], B: [k=kh*8+j][col=lane&31], kh=lane>>5.
template <int H, int F, int NPG>
__global__ __launch_bounds__(2 * (F / 32) * 64)
void k_agg32(const float* __restrict__ U,
             const unsigned short* __restrict__ Vb,
             const float* __restrict__ W2,
             const float* __restrict__ B2,
             const int* __restrict__ rowptr,
             const int* __restrict__ csr_src,
             const int* __restrict__ csr_dst,
             float* __restrict__ Y) {
    constexpr int CWAVES = F / 32;
    constexpr int BLOCK = 2 * CWAVES * 64;
    constexpr int TR = 64;                  // edge rows per tile (2 row groups x 32)
    constexpr int HP = H + 8;               // padded row (bf16), 16B-aligned
    constexpr int KS16 = H / 16;            // k-steps of 16
    constexpr int ACCSTR = F + 1;
    constexpr int LPR = H / 8;
    constexpr int RPP = BLOCK / LPR;
    constexpr int NPASS = TR / RPP;
    static_assert(H % 16 == 0 && TR % RPP == 0 && NPG <= 120, "shape");

    __shared__ unsigned short hs[2][TR * HP];
    __shared__ unsigned accs[NPG * ACCSTR];
    __shared__ int srcA[2][TR];
    __shared__ __align__(4) signed char slotB[2][TR];

    int tid = threadIdx.x;
    int n0 = blockIdx.x * NPG;

    int ln32 = tid & 31;            // MFMA row/col lane
    int kh = (tid >> 5) & 1;        // k-octet selector
    int wv = tid >> 6;
    int rw = wv / CWAVES;           // row group (0,1)
    int cw = wv % CWAVES;           // col wave

    // ---- W2 fragments (one 32-col tile per wave), once ----
    short8 Bf[KS16];
#pragma unroll
    for (int ks = 0; ks < KS16; ks++) {
        int kb = ks * 16 + kh * 8;
        int col = cw * 32 + ln32;
        short8 b;
#pragma unroll
        for (int j = 0; j < 8; j++)
            b[j] = (short)bfbits(W2[(size_t)(kb + j) * F + col]);
        Bf[ks] = b;
    }

    for (int idx = tid; idx < NPG * ACCSTR; idx += BLOCK) accs[idx] = ENC_NEG_INF;

    int e0 = rowptr[n0], e1 = rowptr[n0 + NPG];
    int ntile = (e1 - e0 + TR - 1) / TR;

    int rid = tid / LPR;
    int kk = (tid % LPR) * 8;

    if (tid < TR) {
        int p = e0 + tid;
        int s = 0; signed char sl = -1;
        if (p < e1) { s = csr_src[p]; sl = (signed char)(csr_dst[p] - n0); }
        srcA[0][tid] = s; slotB[0][tid] = sl;
    }
    __syncthreads();

    // MFMA + segmented max for one completed tile
    auto mfma_tile = [&](int buf, char4 sA, char4 sB, char4 sC, char4 sD) {
        f32x16 acc;
#pragma unroll
        for (int j = 0; j < 16; j++) acc[j] = 0.f;

#pragma unroll
        for (int ks = 0; ks < KS16; ks++) {
            short8 a = *(const short8*)&hs[buf][(rw * 32 + ln32) * HP + ks * 16 + kh * 8];
            acc = __builtin_amdgcn_mfma_f32_32x32x16_bf16(a, Bf[ks], acc, 0, 0, 0);
        }

        int colw = cw * 32 + ln32;
#pragma unroll
        for (int rg = 0; rg < 4; rg++) {
            char4 ss = (rg == 0) ? sA : (rg == 1) ? sB : (rg == 2) ? sC : sD;
            float c0 = acc[4 * rg + 0], c1 = acc[4 * rg + 1];
            float c2 = acc[4 * rg + 2], c3 = acc[4 * rg + 3];
            float m3 = c3;
            float m2 = (ss.z == ss.w) ? fmaxf(c2, m3) : c2;
            float m1 = (ss.y == ss.z) ? fmaxf(c1, m2) : c1;
            float m0 = (ss.x == ss.y) ? fmaxf(c0, m1) : c0;
            if (ss.x >= 0)                 atomicMax(&accs[(int)ss.x * ACCSTR + colw], encf(m0));
            if (ss.y >= 0 && ss.y != ss.x) atomicMax(&accs[(int)ss.y * ACCSTR + colw], encf(m1));
            if (ss.z >= 0 && ss.z != ss.y) atomicMax(&accs[(int)ss.z * ACCSTR + colw], encf(m2));
            if (ss.w >= 0 && ss.w != ss.z) atomicMax(&accs[(int)ss.w * ACCSTR + colw], encf(m3));
        }
    };

    char4 sspA = make_char4(-1, -1, -1, -1), sspB = sspA, sspC = sspA, sspD = sspA;
    int prevbuf = 0;
    int rbase = rw * 32 + 4 * kh;   // my C-rows: rbase + 8*rg + {0..3}

    for (int t = 0; t < ntile; t++) {
        int cur = t & 1;

        // (1) tile-t metadata + EARLY V-gathers
        int msrc[NPASS]; int msl[NPASS];
#pragma unroll
        for (int ps = 0; ps < NPASS; ps++) {
            int r = ps * RPP + rid;
            msrc[ps] = srcA[cur][r];
            msl[ps] = slotB[cur][r];
        }
        uint4 vreg[NPASS];
#pragma unroll
        for (int ps = 0; ps < NPASS; ps++)
            vreg[ps] = *(const uint4*)&Vb[(size_t)msrc[ps] * H + kk];
        char4 sscA = *(const char4*)&slotB[cur][rbase + 0];
        char4 sscB = *(const char4*)&slotB[cur][rbase + 8];
        char4 sscC = *(const char4*)&slotB[cur][rbase + 16];
        char4 sscD = *(const char4*)&slotB[cur][rbase + 24];

        // (2) prefetch CSR metadata for tile t+1
        int nsrc = 0; signed char nsl = -1;
        bool hn = (t + 1 < ntile);
        if (hn && tid < TR) {
            int p = e0 + (t + 1) * TR + tid;
            if (p < e1) { nsrc = csr_src[p]; nsl = (signed char)(csr_dst[p] - n0); }
        }

        // (3) MFMA + seg-max for tile t-1
        if (t > 0) mfma_tile(prevbuf, sspA, sspB, sspC, sspD);

        // (4) build hidden tile t
#pragma unroll
        for (int ps = 0; ps < NPASS; ps++) {
            int r = ps * RPP + rid;
            uint4 w;
            if (msl[ps] >= 0) {
                const float4 ua = *(const float4*)&U[(size_t)(n0 + msl[ps]) * H + kk];
                const float4 ub = *(const float4*)&U[(size_t)(n0 + msl[ps]) * H + kk + 4];
                const uint4 vv = vreg[ps];
                w.x = pk2(fmaxf(ua.x + bflo(vv.x), 0.f), fmaxf(ua.y + bfhi(vv.x), 0.f));
                w.y = pk2(fmaxf(ua.z + bflo(vv.y), 0.f), fmaxf(ua.w + bfhi(vv.y), 0.f));
                w.z = pk2(fmaxf(ub.x + bflo(vv.z), 0.f), fmaxf(ub.y + bfhi(vv.z), 0.f));
                w.w = pk2(fmaxf(ub.z + bflo(vv.w), 0.f), fmaxf(ub.w + bfhi(vv.w), 0.f));
            } else {
                w = (uint4){0u, 0u, 0u, 0u};
            }
            *(uint4*)&hs[cur][r * HP + kk] = w;
        }

        // (5) stage next tile's CSR metadata
        if (hn && tid < TR) { srcA[cur ^ 1][tid] = nsrc; slotB[cur ^ 1][tid] = nsl; }

        // (6) one barrier per tile
        __syncthreads();
        sspA = sscA; sspB = sscB; sspC = sscC; sspD = sscD; prevbuf = cur;
    }
    if (ntile > 0) mfma_tile(prevbuf, sspA, sspB, sspC, sspD);
    __syncthreads();

    for (int idx = tid; idx < NPG * F; idx += BLOCK) {
        int sl = idx / F, cc = idx % F;
        float m = decf(accs[sl * ACCSTR + cc]);
        float o = isfinite(m) ? (m + B2[cc]) : 0.f;
        Y[(size_t)(n0 + sl) * F + cc] = o;
    }
}

// ============================ global max-pool + FC ============================
__global__ void k_pool(const float* __restrict__ X3, const int* __restrict__ batch,
                       unsigned* poolEnc) {
    int gph = blockIdx.x;
    int seg = blockIdx.y;
    int c = threadIdx.x;
    int lo = 0, hi = NNODES;
    while (lo < hi) { int mid = (lo + hi) >> 1; if (batch[mid] < gph) lo = mid + 1; else hi = mid; }
    int start = lo;
    hi = NNODES;
    while (lo < hi) { int mid = (lo + hi) >> 1; if (batch[mid] < gph + 1) lo = mid + 1; else hi = mid; }
    int end = lo;
    int chunk = (end - start + 7) >> 3;
    int s = start + seg * chunk;
    int e = min(end, s + chunk);
    float m = -INFINITY;
    for (int n = s; n < e; n++) m = fmaxf(m, X3[(size_t)n * 256 + c]);
    atomicMax(&poolEnc[gph * 256 + c], encf(m));
}

__global__ __launch_bounds__(128) void k_fc(const unsigned* __restrict__ poolEnc,
                                            const float* __restrict__ Wfc,
                                            const float* __restrict__ Bfc,
                                            float* __restrict__ out) {
    __shared__ float p[256];
    int gph = blockIdx.x, c = threadIdx.x;
    for (int k = c; k < 256; k += 128) {
        float m = decf(poolEnc[gph * 256 + k]);
        p[k] = isfinite(m) ? m : 0.f;
    }
    __syncthreads();
    float s = Bfc[c];
    for (int k = 0; k < 256; k++) s += p[k] * Wfc[k * 128 + c];
    out[gph * 128 + c] = s;
}

// ============================ launch ============================
extern "C" void kernel_launch(void* const* d_in, const int* in_sizes, int n_in,
                              void* d_out, int out_size, void* d_ws, size_t ws_size,
                              hipStream_t stream) {
    const float* x     = (const float*)d_in[0];
    const int*   ei    = (const int*)d_in[1];
    const int*   batch = (const int*)d_in[2];
    const float* w1_1 = (const float*)d_in[3];
    const float* b1_1 = (const float*)d_in[4];
    const float* w2_1 = (const float*)d_in[5];
    const float* b2_1 = (const float*)d_in[6];
    const float* w1_2 = (const float*)d_in[7];
    const float* b1_2 = (const float*)d_in[8];
    const float* w2_2 = (const float*)d_in[9];
    const float* b2_2 = (const float*)d_in[10];
    const float* w1_3 = (const float*)d_in[11];
    const float* b1_3 = (const float*)d_in[12];
    const float* w2_3 = (const float*)d_in[13];
    const float* b2_3 = (const float*)d_in[14];
    const float* wfc  = (const float*)d_in[15];
    const float* bfc  = (const float*)d_in[16];
    float* out = (float*)d_out;

    char* ws = (char*)d_ws;
    size_t off = 0;
    auto alloc = [&](size_t bytes) {
        void* p = ws + off;
        off = (off + bytes + 255) & ~(size_t)255;
        return p;
    };
    int* deg      = (int*)alloc((size_t)NNODES * 4);
    int* cursor   = (int*)alloc((size_t)NNODES * 4);
    int* rowptr   = (int*)alloc((size_t)(NNODES + 1) * 4);
    int* bsum     = (int*)alloc(256 * 4);
    int* boff     = (int*)alloc(256 * 4);
    int* csr_src  = (int*)alloc((size_t)NEDGES * 4);
    int* csr_dst  = (int*)alloc((size_t)NEDGES * 4);
    float* U      = (float*)alloc((size_t)NNODES * 256 * 4);
    unsigned short* V = (unsigned short*)alloc((size_t)NNODES * 256 * 2);
    float* x1     = (float*)alloc((size_t)NNODES * 64 * 4);
    float* x2     = (float*)alloc((size_t)NNODES * 128 * 4);
    float* x3     = (float*)alloc((size_t)NNODES * 256 * 4);
    unsigned* poolEnc = (unsigned*)alloc((size_t)NGRAPHS * 256 * 4);
    (void)ws_size; (void)in_sizes; (void)n_in; (void)out_size;

    // CSR by dst (shared across the 3 layers)
    k_init<<<256, 256, 0, stream>>>(deg, cursor, poolEnc);
    k_count<<<NEDGES / 256, 256, 0, stream>>>(ei, deg);
    k_scan1<<<256, 256, 0, stream>>>(deg, rowptr, bsum);
    k_scan2<<<1, 256, 0, stream>>>(bsum, boff);
    k_scan3<<<256, 256, 0, stream>>>(rowptr, boff);
    k_scatter<<<NEDGES / 256, 256, 0, stream>>>(ei, rowptr, cursor, csr_src, csr_dst);

    // layer 1: F_in=3, H=64, F=64   (scalar k_uv; 16x16 k_agg, NPG=32)
    k_uv<3, 64><<<NNODES / 16, 256, 0, stream>>>(x, w1_1, b1_1, U, V);
    k_agg<64, 64, 2, 2, 32><<<NNODES / 32, 256, 0, stream>>>(U, V, w2_1, b2_1, rowptr, csr_src, csr_dst, x1);
    // layer 2: F_in=64, H=128 — MFMA k_uv; 16x16 k_agg 1x8, NPG=32
    k_uv_mfma<64, 128><<<NNODES / 256, 512, 0, stream>>>(x1, w1_2, b1_2, U, V);
    k_agg<128, 128, 1, 8, 32><<<NNODES / 32, 512, 0, stream>>>(U, V, w2_2, b2_2, rowptr, csr_src, csr_dst, x2);
    // layer 3: F_in=128, H=256 — MFMA k_uv; 32x32 k_agg (2x8 waves, 1024 thr, NPG=32)
    k_uv_mfma<128, 256><<<NNODES / 256, 1024, 0, stream>>>(x2, w1_3, b1_3, U, V);
    k_agg32<256, 256, 32><<<NNODES / 32, 1024, 0, stream>>>(U, V, w2_3, b2_3, rowptr, csr_src, csr_dst, x3);

    // global max pool + FC
    k_pool<<<dim3(NGRAPHS, 8), 256, 0, stream>>>(x3, batch, poolEnc);
    k_fc<<<NGRAPHS, 128, 0, stream>>>(poolEnc, wfc, bfc, out);
}

// Round 15
// 731.553 us; speedup vs baseline: 1.3066x; 1.0022x over previous
//
#include <hip/hip_runtime.h>
#include <hip/hip_bf16.h>
#include <math.h>

#define NNODES 65536
#define NEDGES 1048576
#define NGRAPHS 64

typedef __attribute__((ext_vector_type(8))) short short8;
typedef __attribute__((ext_vector_type(4))) float f32x4;
typedef __attribute__((ext_vector_type(16))) float f32x16;

// ---- order-preserving float<->uint encoding for atomicMax-based max ----
__device__ __forceinline__ unsigned encf(float f) {
    unsigned u = __float_as_uint(f);
    return (u & 0x80000000u) ? ~u : (u | 0x80000000u);
}
__device__ __forceinline__ float decf(unsigned u) {
    unsigned v = (u & 0x80000000u) ? (u & 0x7FFFFFFFu) : ~u;
    return __uint_as_float(v);
}
#define ENC_NEG_INF 0x007FFFFFu   // encf(-inf)

// RNE float -> bf16 bits (finite values only)
__device__ __forceinline__ unsigned bfbits(float f) {
    unsigned u = __float_as_uint(f);
    return (u + 0x7FFFu + ((u >> 16) & 1u)) >> 16;
}
__device__ __forceinline__ float bfval(unsigned bits) { return __uint_as_float(bits << 16); }
// HOT path: HW packed RNE convert (1 VALU op / 2 elems). Round-8 lesson:
// __float2bfloat16 is NOT RNE on this toolchain; v_cvt_pk_bf16_f32 is RNE
// in HW and matches bfbits (verified passing rounds 10-14).
__device__ __forceinline__ unsigned pk2(float a, float b) {
    unsigned r;
    asm("v_cvt_pk_bf16_f32 %0, %1, %2" : "=v"(r) : "v"(a), "v"(b));
    return r;   // a -> low 16, b -> high 16
}
__device__ __forceinline__ float bflo(unsigned p) { return __uint_as_float(p << 16); }
__device__ __forceinline__ float bfhi(unsigned p) { return __uint_as_float(p & 0xFFFF0000u); }

// ============================ CSR build ============================
__global__ void k_init(int* deg, int* cursor, unsigned* poolEnc) {
    int i = blockIdx.x * 256 + threadIdx.x;
    if (i < NNODES) { deg[i] = 0; cursor[i] = 0; }
    if (i < NGRAPHS * 256) poolEnc[i] = ENC_NEG_INF;
}

__global__ void k_count(const int* __restrict__ ei, int* deg) {
    int e = blockIdx.x * 256 + threadIdx.x;
    atomicAdd(&deg[ei[NEDGES + e]], 1);
}

__global__ void k_scan1(const int* __restrict__ deg, int* rowptr, int* bsum) {
    __shared__ int s[256];
    int t = threadIdx.x, b = blockIdx.x;
    int v = deg[b * 256 + t];
    s[t] = v;
    __syncthreads();
    for (int off = 1; off < 256; off <<= 1) {
        int x = (t >= off) ? s[t - off] : 0;
        __syncthreads();
        if (t >= off) s[t] += x;
        __syncthreads();
    }
    rowptr[b * 256 + t] = s[t] - v;       // local exclusive
    if (t == 255) bsum[b] = s[255];
}

__global__ void k_scan2(const int* __restrict__ bsum, int* boff) {
    __shared__ int s[256];
    int t = threadIdx.x;
    int v = bsum[t];
    s[t] = v;
    __syncthreads();
    for (int off = 1; off < 256; off <<= 1) {
        int x = (t >= off) ? s[t - off] : 0;
        __syncthreads();
        if (t >= off) s[t] += x;
        __syncthreads();
    }
    boff[t] = s[t] - v;                   // exclusive block offsets
}

__global__ void k_scan3(int* rowptr, const int* __restrict__ boff) {
    int i = blockIdx.x * 256 + threadIdx.x;
    rowptr[i] += boff[blockIdx.x];
    if (i == 0) rowptr[NNODES] = NEDGES;
}

__global__ void k_scatter(const int* __restrict__ ei, const int* __restrict__ rowptr,
                          int* cursor, int* csr_src, int* csr_dst) {
    int e = blockIdx.x * 256 + threadIdx.x;
    int s = ei[e], d = ei[NEDGES + e];
    int pos = rowptr[d] + atomicAdd(&cursor[d], 1);
    csr_src[pos] = s;
    csr_dst[pos] = d;
}

// ============================ U/V precompute ============================
// Scalar VALU version — kept for layer 1 only (FIN=3: no MFMA fit).
template <int FIN, int H>
__global__ __launch_bounds__(256) void k_uv(const float* __restrict__ X,
                                            const float* __restrict__ W1,
                                            const float* __restrict__ B1,
                                            float* __restrict__ U,
                                            unsigned short* __restrict__ Vb) {
    constexpr int NPT = (16 * H) / 256;   // nodes per thread
    __shared__ float xs[16][FIN];
    int tid = threadIdx.x;
    int n0 = blockIdx.x * 16;
    for (int idx = tid; idx < 16 * FIN; idx += 256)
        xs[idx / FIN][idx % FIN] = X[(size_t)(n0 + idx / FIN) * FIN + (idx % FIN)];
    __syncthreads();
    int h = tid & (H - 1);
    int nb = (tid / H) * NPT;
    float u[NPT], v[NPT];
    float bb = B1[h];
#pragma unroll
    for (int n = 0; n < NPT; n++) { u[n] = bb; v[n] = 0.f; }
    for (int f = 0; f < FIN; f++) {
        float wt = W1[f * H + h];
        float wb = W1[(FIN + f) * H + h];
        float wd = wt - wb;
#pragma unroll
        for (int n = 0; n < NPT; n++) {
            float xv = xs[nb + n][f];
            u[n] += xv * wd;
            v[n] += xv * wb;
        }
    }
#pragma unroll
    for (int n = 0; n < NPT; n++) {
        U[(size_t)(n0 + nb + n) * H + h] = u[n];
        Vb[(size_t)(n0 + nb + n) * H + h] = (unsigned short)bfbits(v[n]);
    }
}

// ==================== U/V precompute via MFMA (layers 2,3) ====================
// Split precision (verified round 12): S = Xhi@Whi + Xhi@Wlo + Xlo@Whi.
template <int FIN, int H>
__global__ __launch_bounds__((H / 16) * 64)
void k_uv_mfma(const float* __restrict__ X,
               const float* __restrict__ W1,
               const float* __restrict__ B1,
               float* __restrict__ U,
               unsigned short* __restrict__ Vb) {
    constexpr int WAVES = H / 16;
    constexpr int BLOCK = WAVES * 64;
    constexpr int KS = FIN / 32;          // k-steps
    constexpr int NPB = 16;               // node-tiles (of 16) per block
    constexpr int FP = FIN + 8;           // padded LDS row (bf16 units)
    static_assert(FIN % 32 == 0 && (16 * FIN) % (2 * BLOCK) == 0, "shape");

    __shared__ unsigned short xhi[16 * FP];
    __shared__ unsigned short xlo[16 * FP];

    int tid = threadIdx.x;
    int ln = tid & 15;
    int qd = (tid >> 4) & 3;
    int wv = tid >> 6;
    int col = wv * 16 + ln;

    short8 bth[KS], btl[KS], bbh[KS], bbl[KS];
#pragma unroll
    for (int ks = 0; ks < KS; ks++) {
        int kb = ks * 32 + qd * 8;
        short8 th, tl, bh, bl;
#pragma unroll
        for (int j = 0; j < 8; j++) {
            float wt = W1[(size_t)(kb + j) * H + col];
            float wb = W1[(size_t)(FIN + kb + j) * H + col];
            unsigned thb = bfbits(wt), bhb = bfbits(wb);
            th[j] = (short)thb;
            bh[j] = (short)bhb;
            tl[j] = (short)bfbits(wt - bfval(thb));
            bl[j] = (short)bfbits(wb - bfval(bhb));
        }
        bth[ks] = th; btl[ks] = tl; bbh[ks] = bh; bbl[ks] = bl;
    }

    float bias = B1[col];
    int nbase0 = blockIdx.x * (NPB * 16);

    int sidx = tid * 2;
    int snode = sidx / FIN;               // 0..15
    int sf = sidx % FIN;

    float2 xr = *(const float2*)&X[(size_t)(nbase0 + snode) * FIN + sf];

    for (int t = 0; t < NPB; t++) {
        unsigned h0 = bfbits(xr.x), h1 = bfbits(xr.y);
        unsigned l0 = bfbits(xr.x - bfval(h0));
        unsigned l1 = bfbits(xr.y - bfval(h1));
        *(unsigned*)&xhi[snode * FP + sf] = h0 | (h1 << 16);
        *(unsigned*)&xlo[snode * FP + sf] = l0 | (l1 << 16);
        if (t + 1 < NPB)
            xr = *(const float2*)&X[(size_t)(nbase0 + (t + 1) * 16 + snode) * FIN + sf];
        __syncthreads();

        f32x4 at = (f32x4){0.f, 0.f, 0.f, 0.f};
        f32x4 ab = (f32x4){0.f, 0.f, 0.f, 0.f};
#pragma unroll
        for (int ks = 0; ks < KS; ks++) {
            int ko = ks * 32 + qd * 8;
            short8 ah = *(const short8*)&xhi[ln * FP + ko];
            short8 al = *(const short8*)&xlo[ln * FP + ko];
            at = __builtin_amdgcn_mfma_f32_16x16x32_bf16(ah, bth[ks], at, 0, 0, 0);
            at = __builtin_amdgcn_mfma_f32_16x16x32_bf16(ah, btl[ks], at, 0, 0, 0);
            at = __builtin_amdgcn_mfma_f32_16x16x32_bf16(al, bth[ks], at, 0, 0, 0);
            ab = __builtin_amdgcn_mfma_f32_16x16x32_bf16(ah, bbh[ks], ab, 0, 0, 0);
            ab = __builtin_amdgcn_mfma_f32_16x16x32_bf16(ah, bbl[ks], ab, 0, 0, 0);
            ab = __builtin_amdgcn_mfma_f32_16x16x32_bf16(al, bbh[ks], ab, 0, 0, 0);
        }

        int nb = nbase0 + t * 16 + qd * 4;
#pragma unroll
        for (int j = 0; j < 4; j++) {
            U[(size_t)(nb + j) * H + col] = at[j] - ab[j] + bias;   // X@(Wt-Wb)+b
            Vb[(size_t)(nb + j) * H + col] = (unsigned short)bfbits(ab[j]); // X@Wb
        }
        __syncthreads();   // tile consumed before next overwrite
    }
}

// ================= fused edge-GEMM (MFMA bf16 16x16) + segment-max =================
// Verified round-13 version — layer 1. Round-5 pipeline + pk2 asm + NPG.
template <int H, int F, int RWAVES, int CWAVES, int NPG>
__global__ __launch_bounds__(RWAVES * CWAVES * 64)
void k_agg(const float* __restrict__ U,
           const unsigned short* __restrict__ Vb,
           const float* __restrict__ W2,
           const float* __restrict__ B2,
           const int* __restrict__ rowptr,
           const int* __restrict__ csr_src,
           const int* __restrict__ csr_dst,
           float* __restrict__ Y) {
    constexpr int BLOCK = RWAVES * CWAVES * 64;
    constexpr int TR = 32 * RWAVES;         // edge rows per tile
    constexpr int HP = H + 8;               // padded row (bf16 units), 16B-aligned frags
    constexpr int CPW = F / CWAVES;         // cols per wave
    constexpr int NT = CPW / 16;            // n-tiles per wave
    constexpr int KS = H / 32;              // k-steps
    constexpr int ACCSTR = F + 1;           // bank-spread accumulator stride
    constexpr int LPR = H / 8;              // threads per hidden row (8 elems each)
    constexpr int RPP = BLOCK / LPR;        // rows per construction pass
    constexpr int NPASS = TR / RPP;         // construction passes per tile
    static_assert(H % 32 == 0 && NT >= 1 && RPP >= 1 && TR % RPP == 0, "shape");
    static_assert(NPG <= 120, "slot fits signed char");

    __shared__ unsigned short hs[2][TR * HP];   // double-buffered hidden tile
    __shared__ unsigned accs[NPG * ACCSTR];     // per-slot running max (encoded)
    __shared__ int srcA[2][TR];
    __shared__ __align__(4) signed char slotB[2][TR];

    int tid = threadIdx.x;
    int n0 = blockIdx.x * NPG;

    int ln = tid & 15;              // MFMA n/m lane index
    int qd = (tid >> 4) & 3;        // MFMA quad
    int wv = tid >> 6;
    int rw = wv / CWAVES;           // row group
    int cw = wv % CWAVES;           // col wave

    short8 Bf[NT][KS];
#pragma unroll
    for (int nt = 0; nt < NT; nt++) {
        int col = cw * CPW + nt * 16 + ln;
#pragma unroll
        for (int ks = 0; ks < KS; ks++) {
            int kb = ks * 32 + qd * 8;
            short8 b;
#pragma unroll
            for (int j = 0; j < 8; j++)
                b[j] = (short)bfbits(W2[(size_t)(kb + j) * F + col]);
            Bf[nt][ks] = b;
        }
    }

    for (int idx = tid; idx < NPG * ACCSTR; idx += BLOCK) accs[idx] = ENC_NEG_INF;

    int e0 = rowptr[n0], e1 = rowptr[n0 + NPG];
    int ntile = (e1 - e0 + TR - 1) / TR;

    int rid = tid / LPR;            // construction: my row within a pass
    int kk = (tid % LPR) * 8;       // construction: my 8-elem chunk

    if (tid < TR) {
        int p = e0 + tid;
        int s = 0; signed char sl = -1;
        if (p < e1) { s = csr_src[p]; sl = (signed char)(csr_dst[p] - n0); }
        srcA[0][tid] = s; slotB[0][tid] = sl;
    }
    __syncthreads();

    auto mfma_tile = [&](int buf, char4 s0, char4 s1) {
        f32x4 acc[2][NT];
#pragma unroll
        for (int mt = 0; mt < 2; mt++)
#pragma unroll
            for (int nt = 0; nt < NT; nt++)
                acc[mt][nt] = (f32x4){0.f, 0.f, 0.f, 0.f};

#pragma unroll
        for (int ks = 0; ks < KS; ks++) {
            int ko = ks * 32 + qd * 8;
            short8 a0 = *(const short8*)&hs[buf][(rw * 32 + ln) * HP + ko];
            short8 a1 = *(const short8*)&hs[buf][(rw * 32 + 16 + ln) * HP + ko];
#pragma unroll
            for (int nt = 0; nt < NT; nt++) {
                acc[0][nt] = __builtin_amdgcn_mfma_f32_16x16x32_bf16(a0, Bf[nt][ks], acc[0][nt], 0, 0, 0);
                acc[1][nt] = __builtin_amdgcn_mfma_f32_16x16x32_bf16(a1, Bf[nt][ks], acc[1][nt], 0, 0, 0);
            }
        }

#pragma unroll
        for (int mt = 0; mt < 2; mt++) {
            char4 ss = mt ? s1 : s0;
#pragma unroll
            for (int nt = 0; nt < NT; nt++) {
                int colw = cw * CPW + nt * 16 + ln;
                float c0 = acc[mt][nt][0], c1 = acc[mt][nt][1];
                float c2 = acc[mt][nt][2], c3 = acc[mt][nt][3];
                float m3 = c3;
                float m2 = (ss.z == ss.w) ? fmaxf(c2, m3) : c2;
                float m1 = (ss.y == ss.z) ? fmaxf(c1, m2) : c1;
                float m0 = (ss.x == ss.y) ? fmaxf(c0, m1) : c0;
                if (ss.x >= 0)                 atomicMax(&accs[(int)ss.x * ACCSTR + colw], encf(m0));
                if (ss.y >= 0 && ss.y != ss.x) atomicMax(&accs[(int)ss.y * ACCSTR + colw], encf(m1));
                if (ss.z >= 0 && ss.z != ss.y) atomicMax(&accs[(int)ss.z * ACCSTR + colw], encf(m2));
                if (ss.w >= 0 && ss.w != ss.z) atomicMax(&accs[(int)ss.w * ACCSTR + colw], encf(m3));
            }
        }
    };

    char4 ssp0 = make_char4(-1, -1, -1, -1), ssp1 = make_char4(-1, -1, -1, -1);
    int prevbuf = 0;

    for (int t = 0; t < ntile; t++) {
        int cur = t & 1;

        int msrc[NPASS]; int msl[NPASS];
#pragma unroll
        for (int ps = 0; ps < NPASS; ps++) {
            int r = ps * RPP + rid;
            msrc[ps] = srcA[cur][r];
            msl[ps] = slotB[cur][r];
        }
        uint4 vreg[NPASS];
#pragma unroll
        for (int ps = 0; ps < NPASS; ps++)
            vreg[ps] = *(const uint4*)&Vb[(size_t)msrc[ps] * H + kk];   // src=0 for pad rows: safe
        char4 ssc0 = *(const char4*)&slotB[cur][rw * 32 + qd * 4];
        char4 ssc1 = *(const char4*)&slotB[cur][rw * 32 + 16 + qd * 4];

        int nsrc = 0; signed char nsl = -1;
        bool hn = (t + 1 < ntile);
        if (hn && tid < TR) {
            int p = e0 + (t + 1) * TR + tid;
            if (p < e1) { nsrc = csr_src[p]; nsl = (signed char)(csr_dst[p] - n0); }
        }

        if (t > 0) mfma_tile(prevbuf, ssp0, ssp1);

#pragma unroll
        for (int ps = 0; ps < NPASS; ps++) {
            int r = ps * RPP + rid;
            uint4 w;
            if (msl[ps] >= 0) {
                const float4 ua = *(const float4*)&U[(size_t)(n0 + msl[ps]) * H + kk];
                const float4 ub = *(const float4*)&U[(size_t)(n0 + msl[ps]) * H + kk + 4];
                const uint4 vv = vreg[ps];
                w.x = pk2(fmaxf(ua.x + bflo(vv.x), 0.f), fmaxf(ua.y + bfhi(vv.x), 0.f));
                w.y = pk2(fmaxf(ua.z + bflo(vv.y), 0.f), fmaxf(ua.w + bfhi(vv.y), 0.f));
                w.z = pk2(fmaxf(ub.x + bflo(vv.z), 0.f), fmaxf(ub.y + bfhi(vv.z), 0.f));
                w.w = pk2(fmaxf(ub.z + bflo(vv.w), 0.f), fmaxf(ub.w + bfhi(vv.w), 0.f));
            } else {
                w = (uint4){0u, 0u, 0u, 0u};
            }
            *(uint4*)&hs[cur][r * HP + kk] = w;
        }

        if (hn && tid < TR) { srcA[cur ^ 1][tid] = nsrc; slotB[cur ^ 1][tid] = nsl; }

        __syncthreads();
        ssp0 = ssc0; ssp1 = ssc1; prevbuf = cur;
    }
    if (ntile > 0) mfma_tile(prevbuf, ssp0, ssp1);
    __syncthreads();

    for (int idx = tid; idx < NPG * F; idx += BLOCK) {
        int sl = idx / F, cc = idx % F;
        float m = decf(accs[sl * ACCSTR + cc]);
        float o = isfinite(m) ? (m + B2[cc]) : 0.f;   // empty segment -> 0
        Y[(size_t)(n0 + sl) * F + cc] = o;
    }
}

// ============ fused edge-GEMM (MFMA bf16 32x32) + segment-max — layers 2,3 ============
// 32x32x16 MFMA: one 32-col tile per wave — same B-regs per k as 16-col
// 16x16, DOUBLE flops per A-byte -> A-read redundancy F/32. Round-14
// measured: bank conflicts -> 0 with this shape. Register arithmetic:
// L3 (H=256): Bf 64 + acc 16 + arch ~60 = 140 > 128 cap -> ~16-reg spill
// (WRITE 144MiB, net ~0 vs 16x16 — kept because conflicts=0 and the two
// effects cancel; candidate for future fix).
// L2 (H=128): Bf 32 + acc 16 + arch ~55 = 103 <= 128 -> NO spill (this
// round's change; tripwire: WRITE must be exactly 32 MiB).
// C/D layout (m74/m101): col=lane&31, row=(reg&3)+8*(reg>>2)+4*(lane>>5).
template <int H, int F, int NPG>
__global__ __launch_bounds__(2 * (F / 32) * 64)
void k_agg32(const float* __restrict__ U,
             const unsigned short* __restrict__ Vb,
             const float* __restrict__ W2,
             const float* __restrict__ B2,
             const int* __restrict__ rowptr,
             const int* __restrict__ csr_src,
             const int* __restrict__ csr_dst,
             float* __restrict__ Y) {
    constexpr int CWAVES = F / 32;
    constexpr int BLOCK = 2 * CWAVES * 64;
    constexpr int TR = 64;                  // edge rows per tile (2 row groups x 32)
    constexpr int HP = H + 8;               // padded row (bf16), 16B-aligned
    constexpr int KS16 = H / 16;            // k-steps of 16
    constexpr int ACCSTR = F + 1;
    constexpr int LPR = H / 8;
    constexpr int RPP = BLOCK / LPR;
    constexpr int NPASS = TR / RPP;
    static_assert(H % 16 == 0 && TR % RPP == 0 && NPG <= 120, "shape");

    __shared__ unsigned short hs[2][TR * HP];
    __shared__ unsigned accs[NPG * ACCSTR];
    __shared__ int srcA[2][TR];
    __shared__ __align__(4) signed char slotB[2][TR];

    int tid = threadIdx.x;
    int n0 = blockIdx.x * NPG;

    int ln32 = tid & 31;            // MFMA row/col lane
    int kh = (tid >> 5) & 1;        // k-octet selector
    int wv = tid >> 6;
    int rw = wv / CWAVES;           // row group (0,1)
    int cw = wv % CWAVES;           // col wave

    // ---- W2 fragments (one 32-col tile per wave), once ----
    short8 Bf[KS16];
#pragma unroll
    for (int ks = 0; ks < KS16; ks++) {
        int kb = ks * 16 + kh * 8;
        int col = cw * 32 + ln32;
        short8 b;
#pragma unroll
        for (int j = 0; j < 8; j++)
            b[j] = (short)bfbits(W2[(size_t)(kb + j) * F + col]);
        Bf[ks] = b;
    }

    for (int idx = tid; idx < NPG * ACCSTR; idx += BLOCK) accs[idx] = ENC_NEG_INF;

    int e0 = rowptr[n0], e1 = rowptr[n0 + NPG];
    int ntile = (e1 - e0 + TR - 1) / TR;

    int rid = tid / LPR;
    int kk = (tid % LPR) * 8;

    if (tid < TR) {
        int p = e0 + tid;
        int s = 0; signed char sl = -1;
        if (p < e1) { s = csr_src[p]; sl = (signed char)(csr_dst[p] - n0); }
        srcA[0][tid] = s; slotB[0][tid] = sl;
    }
    __syncthreads();

    // MFMA + segmented max for one completed tile
    auto mfma_tile = [&](int buf, char4 sA, char4 sB, char4 sC, char4 sD) {
        f32x16 acc;
#pragma unroll
        for (int j = 0; j < 16; j++) acc[j] = 0.f;

#pragma unroll
        for (int ks = 0; ks < KS16; ks++) {
            short8 a = *(const short8*)&hs[buf][(rw * 32 + ln32) * HP + ks * 16 + kh * 8];
            acc = __builtin_amdgcn_mfma_f32_32x32x16_bf16(a, Bf[ks], acc, 0, 0, 0);
        }

        int colw = cw * 32 + ln32;
#pragma unroll
        for (int rg = 0; rg < 4; rg++) {
            char4 ss = (rg == 0) ? sA : (rg == 1) ? sB : (rg == 2) ? sC : sD;
            float c0 = acc[4 * rg + 0], c1 = acc[4 * rg + 1];
            float c2 = acc[4 * rg + 2], c3 = acc[4 * rg + 3];
            float m3 = c3;
            float m2 = (ss.z == ss.w) ? fmaxf(c2, m3) : c2;
            float m1 = (ss.y == ss.z) ? fmaxf(c1, m2) : c1;
            float m0 = (ss.x == ss.y) ? fmaxf(c0, m1) : c0;
            if (ss.x >= 0)                 atomicMax(&accs[(int)ss.x * ACCSTR + colw], encf(m0));
            if (ss.y >= 0 && ss.y != ss.x) atomicMax(&accs[(int)ss.y * ACCSTR + colw], encf(m1));
            if (ss.z >= 0 && ss.z != ss.y) atomicMax(&accs[(int)ss.z * ACCSTR + colw], encf(m2));
            if (ss.w >= 0 && ss.w != ss.z) atomicMax(&accs[(int)ss.w * ACCSTR + colw], encf(m3));
        }
    };

    char4 sspA = make_char4(-1, -1, -1, -1), sspB = sspA, sspC = sspA, sspD = sspA;
    int prevbuf = 0;
    int rbase = rw * 32 + 4 * kh;   // my C-rows: rbase + 8*rg + {0..3}

    for (int t = 0; t < ntile; t++) {
        int cur = t & 1;

        // (1) tile-t metadata + EARLY V-gathers
        int msrc[NPASS]; int msl[NPASS];
#pragma unroll
        for (int ps = 0; ps < NPASS; ps++) {
            int r = ps * RPP + rid;
            msrc[ps] = srcA[cur][r];
            msl[ps] = slotB[cur][r];
        }
        uint4 vreg[NPASS];
#pragma unroll
        for (int ps = 0; ps < NPASS; ps++)
            vreg[ps] = *(const uint4*)&Vb[(size_t)msrc[ps] * H + kk];
        char4 sscA = *(const char4*)&slotB[cur][rbase + 0];
        char4 sscB = *(const char4*)&slotB[cur][rbase + 8];
        char4 sscC = *(const char4*)&slotB[cur][rbase + 16];
        char4 sscD = *(const char4*)&slotB[cur][rbase + 24];

        // (2) prefetch CSR metadata for tile t+1
        int nsrc = 0; signed char nsl = -1;
        bool hn = (t + 1 < ntile);
        if (hn && tid < TR) {
            int p = e0 + (t + 1) * TR + tid;
            if (p < e1) { nsrc = csr_src[p]; nsl = (signed char)(csr_dst[p] - n0); }
        }

        // (3) MFMA + seg-max for tile t-1
        if (t > 0) mfma_tile(prevbuf, sspA, sspB, sspC, sspD);

        // (4) build hidden tile t
#pragma unroll
        for (int ps = 0; ps < NPASS; ps++) {
            int r = ps * RPP + rid;
            uint4 w;
            if (msl[ps] >= 0) {
                const float4 ua = *(const float4*)&U[(size_t)(n0 + msl[ps]) * H + kk];
                const float4 ub = *(const float4*)&U[(size_t)(n0 + msl[ps]) * H + kk + 4];
                const uint4 vv = vreg[ps];
                w.x = pk2(fmaxf(ua.x + bflo(vv.x), 0.f), fmaxf(ua.y + bfhi(vv.x), 0.f));
                w.y = pk2(fmaxf(ua.z + bflo(vv.y), 0.f), fmaxf(ua.w + bfhi(vv.y), 0.f));
                w.z = pk2(fmaxf(ub.x + bflo(vv.z), 0.f), fmaxf(ub.y + bfhi(vv.z), 0.f));
                w.w = pk2(fmaxf(ub.z + bflo(vv.w), 0.f), fmaxf(ub.w + bfhi(vv.w), 0.f));
            } else {
                w = (uint4){0u, 0u, 0u, 0u};
            }
            *(uint4*)&hs[cur][r * HP + kk] = w;
        }

        // (5) stage next tile's CSR metadata
        if (hn && tid < TR) { srcA[cur ^ 1][tid] = nsrc; slotB[cur ^ 1][tid] = nsl; }

        // (6) one barrier per tile
        __syncthreads();
        sspA = sscA; sspB = sscB; sspC = sscC; sspD = sscD; prevbuf = cur;
    }
    if (ntile > 0) mfma_tile(prevbuf, sspA, sspB, sspC, sspD);
    __syncthreads();

    for (int idx = tid; idx < NPG * F; idx += BLOCK) {
        int sl = idx / F, cc = idx % F;
        float m = decf(accs[sl * ACCSTR + cc]);
        float o = isfinite(m) ? (m + B2[cc]) : 0.f;
        Y[(size_t)(n0 + sl) * F + cc] = o;
    }
}

// ============================ global max-pool + FC ============================
__global__ void k_pool(const float* __restrict__ X3, const int* __restrict__ batch,
                       unsigned* poolEnc) {
    int gph = blockIdx.x;
    int seg = blockIdx.y;
    int c = threadIdx.x;
    int lo = 0, hi = NNODES;
    while (lo < hi) { int mid = (lo + hi) >> 1; if (batch[mid] < gph) lo = mid + 1; else hi = mid; }
    int start = lo;
    hi = NNODES;
    while (lo < hi) { int mid = (lo + hi) >> 1; if (batch[mid] < gph + 1) lo = mid + 1; else hi = mid; }
    int end = lo;
    int chunk = (end - start + 7) >> 3;
    int s = start + seg * chunk;
    int e = min(end, s + chunk);
    float m = -INFINITY;
    for (int n = s; n < e; n++) m = fmaxf(m, X3[(size_t)n * 256 + c]);
    atomicMax(&poolEnc[gph * 256 + c], encf(m));
}

__global__ __launch_bounds__(128) void k_fc(const unsigned* __restrict__ poolEnc,
                                            const float* __restrict__ Wfc,
                                            const float* __restrict__ Bfc,
                                            float* __restrict__ out) {
    __shared__ float p[256];
    int gph = blockIdx.x, c = threadIdx.x;
    for (int k = c; k < 256; k += 128) {
        float m = decf(poolEnc[gph * 256 + k]);
        p[k] = isfinite(m) ? m : 0.f;
    }
    __syncthreads();
    float s = Bfc[c];
    for (int k = 0; k < 256; k++) s += p[k] * Wfc[k * 128 + c];
    out[gph * 128 + c] = s;
}

// ============================ launch ============================
extern "C" void kernel_launch(void* const* d_in, const int* in_sizes, int n_in,
                              void* d_out, int out_size, void* d_ws, size_t ws_size,
                              hipStream_t stream) {
    const float* x     = (const float*)d_in[0];
    const int*   ei    = (const int*)d_in[1];
    const int*   batch = (const int*)d_in[2];
    const float* w1_1 = (const float*)d_in[3];
    const float* b1_1 = (const float*)d_in[4];
    const float* w2_1 = (const float*)d_in[5];
    const float* b2_1 = (const float*)d_in[6];
    const float* w1_2 = (const float*)d_in[7];
    const float* b1_2 = (const float*)d_in[8];
    const float* w2_2 = (const float*)d_in[9];
    const float* b2_2 = (const float*)d_in[10];
    const float* w1_3 = (const float*)d_in[11];
    const float* b1_3 = (const float*)d_in[12];
    const float* w2_3 = (const float*)d_in[13];
    const float* b2_3 = (const float*)d_in[14];
    const float* wfc  = (const float*)d_in[15];
    const float* bfc  = (const float*)d_in[16];
    float* out = (float*)d_out;

    char* ws = (char*)d_ws;
    size_t off = 0;
    auto alloc = [&](size_t bytes) {
        void* p = ws + off;
        off = (off + bytes + 255) & ~(size_t)255;
        return p;
    };
    int* deg      = (int*)alloc((size_t)NNODES * 4);
    int* cursor   = (int*)alloc((size_t)NNODES * 4);
    int* rowptr   = (int*)alloc((size_t)(NNODES + 1) * 4);
    int* bsum     = (int*)alloc(256 * 4);
    int* boff     = (int*)alloc(256 * 4);
    int* csr_src  = (int*)alloc((size_t)NEDGES * 4);
    int* csr_dst  = (int*)alloc((size_t)NEDGES * 4);
    float* U      = (float*)alloc((size_t)NNODES * 256 * 4);
    unsigned short* V = (unsigned short*)alloc((size_t)NNODES * 256 * 2);
    float* x1     = (float*)alloc((size_t)NNODES * 64 * 4);
    float* x2     = (float*)alloc((size_t)NNODES * 128 * 4);
    float* x3     = (float*)alloc((size_t)NNODES * 256 * 4);
    unsigned* poolEnc = (unsigned*)alloc((size_t)NGRAPHS * 256 * 4);
    (void)ws_size; (void)in_sizes; (void)n_in; (void)out_size;

    // CSR by dst (shared across the 3 layers)
    k_init<<<256, 256, 0, stream>>>(deg, cursor, poolEnc);
    k_count<<<NEDGES / 256, 256, 0, stream>>>(ei, deg);
    k_scan1<<<256, 256, 0, stream>>>(deg, rowptr, bsum);
    k_scan2<<<1, 256, 0, stream>>>(bsum, boff);
    k_scan3<<<256, 256, 0, stream>>>(rowptr, boff);
    k_scatter<<<NEDGES / 256, 256, 0, stream>>>(ei, rowptr, cursor, csr_src, csr_dst);

    // layer 1: F_in=3, H=64, F=64   (scalar k_uv; 16x16 k_agg, NPG=32 — CWAVES
    // already 2, no redundancy gain from 32x32; keep verified version)
    k_uv<3, 64><<<NNODES / 16, 256, 0, stream>>>(x, w1_1, b1_1, U, V);
    k_agg<64, 64, 2, 2, 32><<<NNODES / 32, 256, 0, stream>>>(U, V, w2_1, b2_1, rowptr, csr_src, csr_dst, x1);
    // layer 2: F_in=64, H=128 — MFMA k_uv; 32x32 k_agg (2x4 waves, 512 thr, NPG=32; no spill)
    k_uv_mfma<64, 128><<<NNODES / 256, 512, 0, stream>>>(x1, w1_2, b1_2, U, V);
    k_agg32<128, 128, 32><<<NNODES / 32, 512, 0, stream>>>(U, V, w2_2, b2_2, rowptr, csr_src, csr_dst, x2);
    // layer 3: F_in=128, H=256 — MFMA k_uv; 32x32 k_agg (2x8 waves, 1024 thr, NPG=32)
    k_uv_mfma<128, 256><<<NNODES / 256, 1024, 0, stream>>>(x2, w1_3, b1_3, U, V);
    k_agg32<256, 256, 32><<<NNODES / 32, 1024, 0, stream>>>(U, V, w2_3, b2_3, rowptr, csr_src, csr_dst, x3);

    // global max pool + FC
    k_pool<<<dim3(NGRAPHS, 8), 256, 0, stream>>>(x3, batch, poolEnc);
    k_fc<<<NGRAPHS, 128, 0, stream>>>(poolEnc, wfc, bfc, out);
}

// Round 17
// 704.217 us; speedup vs baseline: 1.3574x; 1.0388x over previous
//
#include <hip/hip_runtime.h>
#include <hip/hip_bf16.h>
#include <math.h>

#define NNODES 65536
#define NEDGES 1048576
#define NGRAPHS 64

typedef __attribute__((ext_vector_type(8))) short short8;
typedef __attribute__((ext_vector_type(4))) float f32x4;
typedef __attribute__((ext_vector_type(16))) float f32x16;

// ---- order-preserving float<->uint encoding for atomicMax-based max ----
__device__ __forceinline__ unsigned encf(float f) {
    unsigned u = __float_as_uint(f);
    return (u & 0x80000000u) ? ~u : (u | 0x80000000u);
}
__device__ __forceinline__ float decf(unsigned u) {
    unsigned v = (u & 0x80000000u) ? (u & 0x7FFFFFFFu) : ~u;
    return __uint_as_float(v);
}
#define ENC_NEG_INF 0x007FFFFFu   // encf(-inf)

// RNE float -> bf16 bits (finite values only)
__device__ __forceinline__ unsigned bfbits(float f) {
    unsigned u = __float_as_uint(f);
    return (u + 0x7FFFu + ((u >> 16) & 1u)) >> 16;
}
__device__ __forceinline__ float bfval(unsigned bits) { return __uint_as_float(bits << 16); }
// HOT path: HW packed RNE convert (1 VALU op / 2 elems). Round-8 lesson:
// __float2bfloat16 is NOT RNE on this toolchain; v_cvt_pk_bf16_f32 is RNE
// in HW and matches bfbits (verified passing rounds 10-15).
__device__ __forceinline__ unsigned pk2(float a, float b) {
    unsigned r;
    asm("v_cvt_pk_bf16_f32 %0, %1, %2" : "=v"(r) : "v"(a), "v"(b));
    return r;   // a -> low 16, b -> high 16
}
__device__ __forceinline__ float bflo(unsigned p) { return __uint_as_float(p << 16); }
__device__ __forceinline__ float bfhi(unsigned p) { return __uint_as_float(p & 0xFFFF0000u); }

// ============================ CSR build ============================
__global__ void k_init(int* deg, int* cursor, unsigned* poolEnc) {
    int i = blockIdx.x * 256 + threadIdx.x;
    if (i < NNODES) { deg[i] = 0; cursor[i] = 0; }
    if (i < NGRAPHS * 256) poolEnc[i] = ENC_NEG_INF;
}

__global__ void k_count(const int* __restrict__ ei, int* deg) {
    int e = blockIdx.x * 256 + threadIdx.x;
    atomicAdd(&deg[ei[NEDGES + e]], 1);
}

__global__ void k_scan1(const int* __restrict__ deg, int* rowptr, int* bsum) {
    __shared__ int s[256];
    int t = threadIdx.x, b = blockIdx.x;
    int v = deg[b * 256 + t];
    s[t] = v;
    __syncthreads();
    for (int off = 1; off < 256; off <<= 1) {
        int x = (t >= off) ? s[t - off] : 0;
        __syncthreads();
        if (t >= off) s[t] += x;
        __syncthreads();
    }
    rowptr[b * 256 + t] = s[t] - v;       // local exclusive
    if (t == 255) bsum[b] = s[255];
}

__global__ void k_scan2(const int* __restrict__ bsum, int* boff) {
    __shared__ int s[256];
    int t = threadIdx.x;
    int v = bsum[t];
    s[t] = v;
    __syncthreads();
    for (int off = 1; off < 256; off <<= 1) {
        int x = (t >= off) ? s[t - off] : 0;
        __syncthreads();
        if (t >= off) s[t] += x;
        __syncthreads();
    }
    boff[t] = s[t] - v;                   // exclusive block offsets
}

__global__ void k_scan3(int* rowptr, const int* __restrict__ boff) {
    int i = blockIdx.x * 256 + threadIdx.x;
    rowptr[i] += boff[blockIdx.x];
    if (i == 0) rowptr[NNODES] = NEDGES;
}

__global__ void k_scatter(const int* __restrict__ ei, const int* __restrict__ rowptr,
                          int* cursor, int* csr_src, int* csr_dst) {
    int e = blockIdx.x * 256 + threadIdx.x;
    int s = ei[e], d = ei[NEDGES + e];
    int pos = rowptr[d] + atomicAdd(&cursor[d], 1);
    csr_src[pos] = s;
    csr_dst[pos] = d;
}

// ============ W2 -> bf16 fragment-ordered prep (for k_agg32's B loads) ============
// W2b[((cw*KS16+ks)*64 + lane)*8 + j] = bf16(W2[k][col]),
// k = ks*16 + (lane>>5)*8 + j, col = cw*32 + (lane&31).
// One coalesced 16B/lane global load per (wave,ks) inside k_agg32 — W2 stays
// L2-resident (128 KB) so the B-operand costs ZERO registers.
template <int H, int F>
__global__ __launch_bounds__(256) void k_w2prep(const float* __restrict__ W2,
                                                unsigned short* __restrict__ W2b) {
    constexpr int KS16 = H / 16;
    int o = blockIdx.x * 256 + threadIdx.x;       // over H*F outputs
    int j = o & 7;
    int lane = (o >> 3) & 63;
    int t = o >> 9;
    int ks = t % KS16;
    int cw = t / KS16;
    int k = ks * 16 + (lane >> 5) * 8 + j;
    int col = cw * 32 + (lane & 31);
    W2b[o] = (unsigned short)bfbits(W2[(size_t)k * F + col]);
}

// ============================ U/V precompute ============================
// Scalar VALU version — kept for layer 1 only (FIN=3: no MFMA fit).
template <int FIN, int H>
__global__ __launch_bounds__(256) void k_uv(const float* __restrict__ X,
                                            const float* __restrict__ W1,
                                            const float* __restrict__ B1,
                                            float* __restrict__ U,
                                            unsigned short* __restrict__ Vb) {
    constexpr int NPT = (16 * H) / 256;   // nodes per thread
    __shared__ float xs[16][FIN];
    int tid = threadIdx.x;
    int n0 = blockIdx.x * 16;
    for (int idx = tid; idx < 16 * FIN; idx += 256)
        xs[idx / FIN][idx % FIN] = X[(size_t)(n0 + idx / FIN) * FIN + (idx % FIN)];
    __syncthreads();
    int h = tid & (H - 1);
    int nb = (tid / H) * NPT;
    float u[NPT], v[NPT];
    float bb = B1[h];
#pragma unroll
    for (int n = 0; n < NPT; n++) { u[n] = bb; v[n] = 0.f; }
    for (int f = 0; f < FIN; f++) {
        float wt = W1[f * H + h];
        float wb = W1[(FIN + f) * H + h];
        float wd = wt - wb;
#pragma unroll
        for (int n = 0; n < NPT; n++) {
            float xv = xs[nb + n][f];
            u[n] += xv * wd;
            v[n] += xv * wb;
        }
    }
#pragma unroll
    for (int n = 0; n < NPT; n++) {
        U[(size_t)(n0 + nb + n) * H + h] = u[n];
        Vb[(size_t)(n0 + nb + n) * H + h] = (unsigned short)bfbits(v[n]);
    }
}

// ==================== U/V precompute via MFMA (layers 2,3) ====================
// Split precision (verified round 12): S = Xhi@Whi + Xhi@Wlo + Xlo@Whi.
template <int FIN, int H>
__global__ __launch_bounds__((H / 16) * 64)
void k_uv_mfma(const float* __restrict__ X,
               const float* __restrict__ W1,
               const float* __restrict__ B1,
               float* __restrict__ U,
               unsigned short* __restrict__ Vb) {
    constexpr int WAVES = H / 16;
    constexpr int BLOCK = WAVES * 64;
    constexpr int KS = FIN / 32;          // k-steps
    constexpr int NPB = 16;               // node-tiles (of 16) per block
    constexpr int FP = FIN + 8;           // padded LDS row (bf16 units)
    static_assert(FIN % 32 == 0 && (16 * FIN) % (2 * BLOCK) == 0, "shape");

    __shared__ unsigned short xhi[16 * FP];
    __shared__ unsigned short xlo[16 * FP];

    int tid = threadIdx.x;
    int ln = tid & 15;
    int qd = (tid >> 4) & 3;
    int wv = tid >> 6;
    int col = wv * 16 + ln;

    short8 bth[KS], btl[KS], bbh[KS], bbl[KS];
#pragma unroll
    for (int ks = 0; ks < KS; ks++) {
        int kb = ks * 32 + qd * 8;
        short8 th, tl, bh, bl;
#pragma unroll
        for (int j = 0; j < 8; j++) {
            float wt = W1[(size_t)(kb + j) * H + col];
            float wb = W1[(size_t)(FIN + kb + j) * H + col];
            unsigned thb = bfbits(wt), bhb = bfbits(wb);
            th[j] = (short)thb;
            bh[j] = (short)bhb;
            tl[j] = (short)bfbits(wt - bfval(thb));
            bl[j] = (short)bfbits(wb - bfval(bhb));
        }
        bth[ks] = th; btl[ks] = tl; bbh[ks] = bh; bbl[ks] = bl;
    }

    float bias = B1[col];
    int nbase0 = blockIdx.x * (NPB * 16);

    int sidx = tid * 2;
    int snode = sidx / FIN;               // 0..15
    int sf = sidx % FIN;

    float2 xr = *(const float2*)&X[(size_t)(nbase0 + snode) * FIN + sf];

    for (int t = 0; t < NPB; t++) {
        unsigned h0 = bfbits(xr.x), h1 = bfbits(xr.y);
        unsigned l0 = bfbits(xr.x - bfval(h0));
        unsigned l1 = bfbits(xr.y - bfval(h1));
        *(unsigned*)&xhi[snode * FP + sf] = h0 | (h1 << 16);
        *(unsigned*)&xlo[snode * FP + sf] = l0 | (l1 << 16);
        if (t + 1 < NPB)
            xr = *(const float2*)&X[(size_t)(nbase0 + (t + 1) * 16 + snode) * FIN + sf];
        __syncthreads();

        f32x4 at = (f32x4){0.f, 0.f, 0.f, 0.f};
        f32x4 ab = (f32x4){0.f, 0.f, 0.f, 0.f};
#pragma unroll
        for (int ks = 0; ks < KS; ks++) {
            int ko = ks * 32 + qd * 8;
            short8 ah = *(const short8*)&xhi[ln * FP + ko];
            short8 al = *(const short8*)&xlo[ln * FP + ko];
            at = __builtin_amdgcn_mfma_f32_16x16x32_bf16(ah, bth[ks], at, 0, 0, 0);
            at = __builtin_amdgcn_mfma_f32_16x16x32_bf16(ah, btl[ks], at, 0, 0, 0);
            at = __builtin_amdgcn_mfma_f32_16x16x32_bf16(al, bth[ks], at, 0, 0, 0);
            ab = __builtin_amdgcn_mfma_f32_16x16x32_bf16(ah, bbh[ks], ab, 0, 0, 0);
            ab = __builtin_amdgcn_mfma_f32_16x16x32_bf16(ah, bbl[ks], ab, 0, 0, 0);
            ab = __builtin_amdgcn_mfma_f32_16x16x32_bf16(al, bbh[ks], ab, 0, 0, 0);
        }

        int nb = nbase0 + t * 16 + qd * 4;
#pragma unroll
        for (int j = 0; j < 4; j++) {
            U[(size_t)(nb + j) * H + col] = at[j] - ab[j] + bias;   // X@(Wt-Wb)+b
            Vb[(size_t)(nb + j) * H + col] = (unsigned short)bfbits(ab[j]); // X@Wb
        }
        __syncthreads();   // tile consumed before next overwrite
    }
}

// ================= fused edge-GEMM (MFMA bf16 16x16) + segment-max =================
// Verified round-13 version — layer 1. Round-5 pipeline + pk2 asm + NPG.
template <int H, int F, int RWAVES, int CWAVES, int NPG>
__global__ __launch_bounds__(RWAVES * CWAVES * 64)
void k_agg(const float* __restrict__ U,
           const unsigned short* __restrict__ Vb,
           const float* __restrict__ W2,
           const float* __restrict__ B2,
           const int* __restrict__ rowptr,
           const int* __restrict__ csr_src,
           const int* __restrict__ csr_dst,
           float* __restrict__ Y) {
    constexpr int BLOCK = RWAVES * CWAVES * 64;
    constexpr int TR = 32 * RWAVES;         // edge rows per tile
    constexpr int HP = H + 8;               // padded row (bf16 units), 16B-aligned frags
    constexpr int CPW = F / CWAVES;         // cols per wave
    constexpr int NT = CPW / 16;            // n-tiles per wave
    constexpr int KS = H / 32;              // k-steps
    constexpr int ACCSTR = F + 1;           // bank-spread accumulator stride
    constexpr int LPR = H / 8;              // threads per hidden row (8 elems each)
    constexpr int RPP = BLOCK / LPR;        // rows per construction pass
    constexpr int NPASS = TR / RPP;         // construction passes per tile
    static_assert(H % 32 == 0 && NT >= 1 && RPP >= 1 && TR % RPP == 0, "shape");
    static_assert(NPG <= 120, "slot fits signed char");

    __shared__ unsigned short hs[2][TR * HP];   // double-buffered hidden tile
    __shared__ unsigned accs[NPG * ACCSTR];     // per-slot running max (encoded)
    __shared__ int srcA[2][TR];
    __shared__ __align__(4) signed char slotB[2][TR];

    int tid = threadIdx.x;
    int n0 = blockIdx.x * NPG;

    int ln = tid & 15;              // MFMA n/m lane index
    int qd = (tid >> 4) & 3;        // MFMA quad
    int wv = tid >> 6;
    int rw = wv / CWAVES;           // row group
    int cw = wv % CWAVES;           // col wave

    short8 Bf[NT][KS];
#pragma unroll
    for (int nt = 0; nt < NT; nt++) {
        int col = cw * CPW + nt * 16 + ln;
#pragma unroll
        for (int ks = 0; ks < KS; ks++) {
            int kb = ks * 32 + qd * 8;
            short8 b;
#pragma unroll
            for (int j = 0; j < 8; j++)
                b[j] = (short)bfbits(W2[(size_t)(kb + j) * F + col]);
            Bf[nt][ks] = b;
        }
    }

    for (int idx = tid; idx < NPG * ACCSTR; idx += BLOCK) accs[idx] = ENC_NEG_INF;

    int e0 = rowptr[n0], e1 = rowptr[n0 + NPG];
    int ntile = (e1 - e0 + TR - 1) / TR;

    int rid = tid / LPR;            // construction: my row within a pass
    int kk = (tid % LPR) * 8;       // construction: my 8-elem chunk

    if (tid < TR) {
        int p = e0 + tid;
        int s = 0; signed char sl = -1;
        if (p < e1) { s = csr_src[p]; sl = (signed char)(csr_dst[p] - n0); }
        srcA[0][tid] = s; slotB[0][tid] = sl;
    }
    __syncthreads();

    auto mfma_tile = [&](int buf, char4 s0, char4 s1) {
        f32x4 acc[2][NT];
#pragma unroll
        for (int mt = 0; mt < 2; mt++)
#pragma unroll
            for (int nt = 0; nt < NT; nt++)
                acc[mt][nt] = (f32x4){0.f, 0.f, 0.f, 0.f};

#pragma unroll
        for (int ks = 0; ks < KS; ks++) {
            int ko = ks * 32 + qd * 8;
            short8 a0 = *(const short8*)&hs[buf][(rw * 32 + ln) * HP + ko];
            short8 a1 = *(const short8*)&hs[buf][(rw * 32 + 16 + ln) * HP + ko];
#pragma unroll
            for (int nt = 0; nt < NT; nt++) {
                acc[0][nt] = __builtin_amdgcn_mfma_f32_16x16x32_bf16(a0, Bf[nt][ks], acc[0][nt], 0, 0, 0);
                acc[1][nt] = __builtin_amdgcn_mfma_f32_16x16x32_bf16(a1, Bf[nt][ks], acc[1][nt], 0, 0, 0);
            }
        }

#pragma unroll
        for (int mt = 0; mt < 2; mt++) {
            char4 ss = mt ? s1 : s0;
#pragma unroll
            for (int nt = 0; nt < NT; nt++) {
                int colw = cw * CPW + nt * 16 + ln;
                float c0 = acc[mt][nt][0], c1 = acc[mt][nt][1];
                float c2 = acc[mt][nt][2], c3 = acc[mt][nt][3];
                float m3 = c3;
                float m2 = (ss.z == ss.w) ? fmaxf(c2, m3) : c2;
                float m1 = (ss.y == ss.z) ? fmaxf(c1, m2) : c1;
                float m0 = (ss.x == ss.y) ? fmaxf(c0, m1) : c0;
                if (ss.x >= 0)                 atomicMax(&accs[(int)ss.x * ACCSTR + colw], encf(m0));
                if (ss.y >= 0 && ss.y != ss.x) atomicMax(&accs[(int)ss.y * ACCSTR + colw], encf(m1));
                if (ss.z >= 0 && ss.z != ss.y) atomicMax(&accs[(int)ss.z * ACCSTR + colw], encf(m2));
                if (ss.w >= 0 && ss.w != ss.z) atomicMax(&accs[(int)ss.w * ACCSTR + colw], encf(m3));
            }
        }
    };

    char4 ssp0 = make_char4(-1, -1, -1, -1), ssp1 = make_char4(-1, -1, -1, -1);
    int prevbuf = 0;

    for (int t = 0; t < ntile; t++) {
        int cur = t & 1;

        int msrc[NPASS]; int msl[NPASS];
#pragma unroll
        for (int ps = 0; ps < NPASS; ps++) {
            int r = ps * RPP + rid;
            msrc[ps] = srcA[cur][r];
            msl[ps] = slotB[cur][r];
        }
        uint4 vreg[NPASS];
#pragma unroll
        for (int ps = 0; ps < NPASS; ps++)
            vreg[ps] = *(const uint4*)&Vb[(size_t)msrc[ps] * H + kk];   // src=0 for pad rows: safe
        char4 ssc0 = *(const char4*)&slotB[cur][rw * 32 + qd * 4];
        char4 ssc1 = *(const char4*)&slotB[cur][rw * 32 + 16 + qd * 4];

        int nsrc = 0; signed char nsl = -1;
        bool hn = (t + 1 < ntile);
        if (hn && tid < TR) {
            int p = e0 + (t + 1) * TR + tid;
            if (p < e1) { nsrc = csr_src[p]; nsl = (signed char)(csr_dst[p] - n0); }
        }

        if (t > 0) mfma_tile(prevbuf, ssp0, ssp1);

#pragma unroll
        for (int ps = 0; ps < NPASS; ps++) {
            int r = ps * RPP + rid;
            uint4 w;
            if (msl[ps] >= 0) {
                const float4 ua = *(const float4*)&U[(size_t)(n0 + msl[ps]) * H + kk];
                const float4 ub = *(const float4*)&U[(size_t)(n0 + msl[ps]) * H + kk + 4];
                const uint4 vv = vreg[ps];
                w.x = pk2(fmaxf(ua.x + bflo(vv.x), 0.f), fmaxf(ua.y + bfhi(vv.x), 0.f));
                w.y = pk2(fmaxf(ua.z + bflo(vv.y), 0.f), fmaxf(ua.w + bfhi(vv.y), 0.f));
                w.z = pk2(fmaxf(ub.x + bflo(vv.z), 0.f), fmaxf(ub.y + bfhi(vv.z), 0.f));
                w.w = pk2(fmaxf(ub.z + bflo(vv.w), 0.f), fmaxf(ub.w + bfhi(vv.w), 0.f));
            } else {
                w = (uint4){0u, 0u, 0u, 0u};
            }
            *(uint4*)&hs[cur][r * HP + kk] = w;
        }

        if (hn && tid < TR) { srcA[cur ^ 1][tid] = nsrc; slotB[cur ^ 1][tid] = nsl; }

        __syncthreads();
        ssp0 = ssc0; ssp1 = ssc1; prevbuf = cur;
    }
    if (ntile > 0) mfma_tile(prevbuf, ssp0, ssp1);
    __syncthreads();

    for (int idx = tid; idx < NPG * F; idx += BLOCK) {
        int sl = idx / F, cc = idx % F;
        float m = decf(accs[sl * ACCSTR + cc]);
        float o = isfinite(m) ? (m + B2[cc]) : 0.f;   // empty segment -> 0
        Y[(size_t)(n0 + sl) * F + cc] = o;
    }
}

// ============ fused edge-GEMM (MFMA bf16 32x32) + segment-max — layers 2,3 ============
// 32x32x16 MFMA (conflicts=0, A-redundancy F/32). Round-16 change: B-operand
// no longer register-resident (was 64 regs @H=256 -> 16-reg spill, 144MiB
// writes). W2b is pre-converted bf16 in FRAGMENT ORDER: each (wave,ks) frag
// is one coalesced 16B/lane global load, L2-resident (W2b <= 128 KB).
// Register demand drops to acc 16 + arch ~60 -> no spill.
template <int H, int F, int NPG>
__global__ __launch_bounds__(2 * (F / 32) * 64)
void k_agg32(const float* __restrict__ U,
             const unsigned short* __restrict__ Vb,
             const unsigned short* __restrict__ W2b,
             const float* __restrict__ B2,
             const int* __restrict__ rowptr,
             const int* __restrict__ csr_src,
             const int* __restrict__ csr_dst,
             float* __restrict__ Y) {
    constexpr int CWAVES = F / 32;
    constexpr int BLOCK = 2 * CWAVES * 64;
    constexpr int TR = 64;                  // edge rows per tile (2 row groups x 32)
    constexpr int HP = H + 8;               // padded row (bf16), 16B-aligned
    constexpr int KS16 = H / 16;            // k-steps of 16
    constexpr int ACCSTR = F + 1;
    constexpr int LPR = H / 8;
    constexpr int RPP = BLOCK / LPR;
    constexpr int NPASS = TR / RPP;
    static_assert(H % 16 == 0 && TR % RPP == 0 && NPG <= 120, "shape");

    __shared__ unsigned short hs[2][TR * HP];
    __shared__ unsigned accs[NPG * ACCSTR];
    __shared__ int srcA[2][TR];
    __shared__ __align__(4) signed char slotB[2][TR];

    int tid = threadIdx.x;
    int n0 = blockIdx.x * NPG;

    int ln32 = tid & 31;            // MFMA row/col lane
    int kh = (tid >> 5) & 1;        // k-octet selector
    int wv = tid >> 6;
    int rw = wv / CWAVES;           // row group (0,1)
    int cw = wv % CWAVES;           // col wave

    // per-lane base into fragment-ordered W2b: frag(cw,ks) at ((cw*KS16+ks)*64+lane)*8
    const unsigned short* Bp = W2b + ((size_t)(cw * KS16) * 64 + (tid & 63)) * 8;

    for (int idx = tid; idx < NPG * ACCSTR; idx += BLOCK) accs[idx] = ENC_NEG_INF;

    int e0 = rowptr[n0], e1 = rowptr[n0 + NPG];
    int ntile = (e1 - e0 + TR - 1) / TR;

    int rid = tid / LPR;
    int kk = (tid % LPR) * 8;

    if (tid < TR) {
        int p = e0 + tid;
        int s = 0; signed char sl = -1;
        if (p < e1) { s = csr_src[p]; sl = (signed char)(csr_dst[p] - n0); }
        srcA[0][tid] = s; slotB[0][tid] = sl;
    }
    __syncthreads();

    // MFMA + segmented max for one completed tile (B-frags streamed from L2)
    auto mfma_tile = [&](int buf, char4 sA, char4 sB, char4 sC, char4 sD) {
        f32x16 acc;
#pragma unroll
        for (int j = 0; j < 16; j++) acc[j] = 0.f;

#pragma unroll
        for (int ks = 0; ks < KS16; ks++) {
            short8 a = *(const short8*)&hs[buf][(rw * 32 + ln32) * HP + ks * 16 + kh * 8];
            short8 b = *(const short8*)&Bp[(size_t)ks * 64 * 8];
            acc = __builtin_amdgcn_mfma_f32_32x32x16_bf16(a, b, acc, 0, 0, 0);
        }

        int colw = cw * 32 + ln32;
#pragma unroll
        for (int rg = 0; rg < 4; rg++) {
            char4 ss = (rg == 0) ? sA : (rg == 1) ? sB : (rg == 2) ? sC : sD;
            float c0 = acc[4 * rg + 0], c1 = acc[4 * rg + 1];
            float c2 = acc[4 * rg + 2], c3 = acc[4 * rg + 3];
            float m3 = c3;
            float m2 = (ss.z == ss.w) ? fmaxf(c2, m3) : c2;
            float m1 = (ss.y == ss.z) ? fmaxf(c1, m2) : c1;
            float m0 = (ss.x == ss.y) ? fmaxf(c0, m1) : c0;
            if (ss.x >= 0)                 atomicMax(&accs[(int)ss.x * ACCSTR + colw], encf(m0));
            if (ss.y >= 0 && ss.y != ss.x) atomicMax(&accs[(int)ss.y * ACCSTR + colw], encf(m1));
            if (ss.z >= 0 && ss.z != ss.y) atomicMax(&accs[(int)ss.z * ACCSTR + colw], encf(m2));
            if (ss.w >= 0 && ss.w != ss.z) atomicMax(&accs[(int)ss.w * ACCSTR + colw], encf(m3));
        }
    };

    char4 sspA = make_char4(-1, -1, -1, -1), sspB = sspA, sspC = sspA, sspD = sspA;
    int prevbuf = 0;
    int rbase = rw * 32 + 4 * kh;   // my C-rows: rbase + 8*rg + {0..3}

    for (int t = 0; t < ntile; t++) {
        int cur = t & 1;

        // (1) tile-t metadata + EARLY V-gathers
        int msrc[NPASS]; int msl[NPASS];
#pragma unroll
        for (int ps = 0; ps < NPASS; ps++) {
            int r = ps * RPP + rid;
            msrc[ps] = srcA[cur][r];
            msl[ps] = slotB[cur][r];
        }
        uint4 vreg[NPASS];
#pragma unroll
        for (int ps = 0; ps < NPASS; ps++)
            vreg[ps] = *(const uint4*)&Vb[(size_t)msrc[ps] * H + kk];
        char4 sscA = *(const char4*)&slotB[cur][rbase + 0];
        char4 sscB = *(const char4*)&slotB[cur][rbase + 8];
        char4 sscC = *(const char4*)&slotB[cur][rbase + 16];
        char4 sscD = *(const char4*)&slotB[cur][rbase + 24];

        // (2) prefetch CSR metadata for tile t+1
        int nsrc = 0; signed char nsl = -1;
        bool hn = (t + 1 < ntile);
        if (hn && tid < TR) {
            int p = e0 + (t + 1) * TR + tid;
            if (p < e1) { nsrc = csr_src[p]; nsl = (signed char)(csr_dst[p] - n0); }
        }

        // (3) MFMA + seg-max for tile t-1
        if (t > 0) mfma_tile(prevbuf, sspA, sspB, sspC, sspD);

        // (4) build hidden tile t
#pragma unroll
        for (int ps = 0; ps < NPASS; ps++) {
            int r = ps * RPP + rid;
            uint4 w;
            if (msl[ps] >= 0) {
                const float4 ua = *(const float4*)&U[(size_t)(n0 + msl[ps]) * H + kk];
                const float4 ub = *(const float4*)&U[(size_t)(n0 + msl[ps]) * H + kk + 4];
                const uint4 vv = vreg[ps];
                w.x = pk2(fmaxf(ua.x + bflo(vv.x), 0.f), fmaxf(ua.y + bfhi(vv.x), 0.f));
                w.y = pk2(fmaxf(ua.z + bflo(vv.y), 0.f), fmaxf(ua.w + bfhi(vv.y), 0.f));
                w.z = pk2(fmaxf(ub.x + bflo(vv.z), 0.f), fmaxf(ub.y + bfhi(vv.z), 0.f));
                w.w = pk2(fmaxf(ub.z + bflo(vv.w), 0.f), fmaxf(ub.w + bfhi(vv.w), 0.f));
            } else {
                w = (uint4){0u, 0u, 0u, 0u};
            }
            *(uint4*)&hs[cur][r * HP + kk] = w;
        }

        // (5) stage next tile's CSR metadata
        if (hn && tid < TR) { srcA[cur ^ 1][tid] = nsrc; slotB[cur ^ 1][tid] = nsl; }

        // (6) one barrier per tile
        __syncthreads();
        sspA = sscA; sspB = sscB; sspC = sscC; sspD = sscD; prevbuf = cur;
    }
    if (ntile > 0) mfma_tile(prevbuf, sspA, sspB, sspC, sspD);
    __syncthreads();

    for (int idx = tid; idx < NPG * F; idx += BLOCK) {
        int sl = idx / F, cc = idx % F;
        float m = decf(accs[sl * ACCSTR + cc]);
        float o = isfinite(m) ? (m + B2[cc]) : 0.f;
        Y[(size_t)(n0 + sl) * F + cc] = o;
    }
}

// ============================ global max-pool + FC ============================
__global__ void k_pool(const float* __restrict__ X3, const int* __restrict__ batch,
                       unsigned* poolEnc) {
    int gph = blockIdx.x;
    int seg = blockIdx.y;
    int c = threadIdx.x;
    int lo = 0, hi = NNODES;
    while (lo < hi) { int mid = (lo + hi) >> 1; if (batch[mid] < gph) lo = mid + 1; else hi = mid; }
    int start = lo;
    hi = NNODES;
    while (lo < hi) { int mid = (lo + hi) >> 1; if (batch[mid] < gph + 1) lo = mid + 1; else hi = mid; }
    int end = lo;
    int chunk = (end - start + 7) >> 3;
    int s = start + seg * chunk;
    int e = min(end, s + chunk);
    float m = -INFINITY;
    for (int n = s; n < e; n++) m = fmaxf(m, X3[(size_t)n * 256 + c]);
    atomicMax(&poolEnc[gph * 256 + c], encf(m));
}

__global__ __launch_bounds__(128) void k_fc(const unsigned* __restrict__ poolEnc,
                                            const float* __restrict__ Wfc,
                                            const float* __restrict__ Bfc,
                                            float* __restrict__ out) {
    __shared__ float p[256];
    int gph = blockIdx.x, c = threadIdx.x;
    for (int k = c; k < 256; k += 128) {
        float m = decf(poolEnc[gph * 256 + k]);
        p[k] = isfinite(m) ? m : 0.f;
    }
    __syncthreads();
    float s = Bfc[c];
    for (int k = 0; k < 256; k++) s += p[k] * Wfc[k * 128 + c];
    out[gph * 128 + c] = s;
}

// ============================ launch ============================
extern "C" void kernel_launch(void* const* d_in, const int* in_sizes, int n_in,
                              void* d_out, int out_size, void* d_ws, size_t ws_size,
                              hipStream_t stream) {
    const float* x     = (const float*)d_in[0];
    const int*   ei    = (const int*)d_in[1];
    const int*   batch = (const int*)d_in[2];
    const float* w1_1 = (const float*)d_in[3];
    const float* b1_1 = (const float*)d_in[4];
    const float* w2_1 = (const float*)d_in[5];
    const float* b2_1 = (const float*)d_in[6];
    const float* w1_2 = (const float*)d_in[7];
    const float* b1_2 = (const float*)d_in[8];
    const float* w2_2 = (const float*)d_in[9];
    const float* b2_2 = (const float*)d_in[10];
    const float* w1_3 = (const float*)d_in[11];
    const float* b1_3 = (const float*)d_in[12];
    const float* w2_3 = (const float*)d_in[13];
    const float* b2_3 = (const float*)d_in[14];
    const float* wfc  = (const float*)d_in[15];
    const float* bfc  = (const float*)d_in[16];
    float* out = (float*)d_out;

    char* ws = (char*)d_ws;
    size_t off = 0;
    auto alloc = [&](size_t bytes) {
        void* p = ws + off;
        off = (off + bytes + 255) & ~(size_t)255;
        return p;
    };
    int* deg      = (int*)alloc((size_t)NNODES * 4);
    int* cursor   = (int*)alloc((size_t)NNODES * 4);
    int* rowptr   = (int*)alloc((size_t)(NNODES + 1) * 4);
    int* bsum     = (int*)alloc(256 * 4);
    int* boff     = (int*)alloc(256 * 4);
    int* csr_src  = (int*)alloc((size_t)NEDGES * 4);
    int* csr_dst  = (int*)alloc((size_t)NEDGES * 4);
    float* U      = (float*)alloc((size_t)NNODES * 256 * 4);
    unsigned short* V = (unsigned short*)alloc((size_t)NNODES * 256 * 2);
    float* x1     = (float*)alloc((size_t)NNODES * 64 * 4);
    float* x2     = (float*)alloc((size_t)NNODES * 128 * 4);
    float* x3     = (float*)alloc((size_t)NNODES * 256 * 4);
    unsigned* poolEnc = (unsigned*)alloc((size_t)NGRAPHS * 256 * 4);
    unsigned short* w2b2 = (unsigned short*)alloc((size_t)128 * 128 * 2);
    unsigned short* w2b3 = (unsigned short*)alloc((size_t)256 * 256 * 2);
    (void)ws_size; (void)in_sizes; (void)n_in; (void)out_size;

    // CSR by dst (shared across the 3 layers) + W2 fragment prep
    k_init<<<256, 256, 0, stream>>>(deg, cursor, poolEnc);
    k_count<<<NEDGES / 256, 256, 0, stream>>>(ei, deg);
    k_scan1<<<256, 256, 0, stream>>>(deg, rowptr, bsum);
    k_scan2<<<1, 256, 0, stream>>>(bsum, boff);
    k_scan3<<<256, 256, 0, stream>>>(rowptr, boff);
    k_scatter<<<NEDGES / 256, 256, 0, stream>>>(ei, rowptr, cursor, csr_src, csr_dst);
    k_w2prep<128, 128><<<(128 * 128) / 256, 256, 0, stream>>>(w2_2, w2b2);
    k_w2prep<256, 256><<<(256 * 256) / 256, 256, 0, stream>>>(w2_3, w2b3);

    // layer 1: F_in=3, H=64, F=64   (scalar k_uv; 16x16 k_agg, NPG=32)
    k_uv<3, 64><<<NNODES / 16, 256, 0, stream>>>(x, w1_1, b1_1, U, V);
    k_agg<64, 64, 2, 2, 32><<<NNODES / 32, 256, 0, stream>>>(U, V, w2_1, b2_1, rowptr, csr_src, csr_dst, x1);
    // layer 2: F_in=64, H=128 — MFMA k_uv; 32x32 k_agg (2x4 waves, 512 thr, NPG=32, streamed B)
    k_uv_mfma<64, 128><<<NNODES / 256, 512, 0, stream>>>(x1, w1_2, b1_2, U, V);
    k_agg32<128, 128, 32><<<NNODES / 32, 512, 0, stream>>>(U, V, w2b2, b2_2, rowptr, csr_src, csr_dst, x2);
    // layer 3: F_in=128, H=256 — MFMA k_uv; 32x32 k_agg (2x8 waves, 1024 thr, NPG=32, streamed B)
    k_uv_mfma<128, 256><<<NNODES / 256, 1024, 0, stream>>>(x2, w1_3, b1_3, U, V);
    k_agg32<256, 256, 32><<<NNODES / 32, 1024, 0, stream>>>(U, V, w2b3, b2_3, rowptr, csr_src, csr_dst, x3);

    // global max pool + FC
    k_pool<<<dim3(NGRAPHS, 8), 256, 0, stream>>>(x3, batch, poolEnc);
    k_fc<<<NGRAPHS, 128, 0, stream>>>(poolEnc, wfc, bfc, out);
}